// Round 1
// baseline (2838.783 us; speedup 1.0000x reference)
//
#include <hip/hip_runtime.h>
#include <math.h>
#include <float.h>

#define N_NODES 1024
#define IN_CH   1433
#define HID     16
#define OUT_CH  7
#define N_EDGES 4096
#define E_TOT   5120   // N_EDGES + N_NODES (self loops)
#define N_TE    5119   // embedded series length
#define SP      5120   // pitch for per-channel sorted arrays

// psi(x) for integer-valued x >= 1. Recurrence to x>=6 then asymptotic.
// digammaf_dev(0) = -inf, matching jax digamma(0) for the degenerate eps==0 case.
__device__ __forceinline__ float digammaf_dev(float x) {
    float r = 0.0f;
    while (x < 6.0f) { r -= 1.0f / x; x += 1.0f; }
    float inv  = 1.0f / x;
    float inv2 = inv * inv;
    r += logf(x) - 0.5f * inv
       - inv2 * (1.0f/12.0f - inv2 * (1.0f/120.0f - inv2 * (1.0f/252.0f)));
    return r;
}

// h1[r][o] = sum_k x[r][k] * W1[o][k] + b1[o].  One block per row.
__global__ __launch_bounds__(256) void gemm1_kernel(
    const float* __restrict__ x, const float* __restrict__ W1,
    const float* __restrict__ b1, float* __restrict__ h1) {
    __shared__ float xrow[IN_CH];
    const int r = blockIdx.x;
    const float* xr = x + (size_t)r * IN_CH;
    for (int k = threadIdx.x; k < IN_CH; k += 256) xrow[k] = xr[k];
    __syncthreads();
    const int o = threadIdx.x >> 4;
    const int g = threadIdx.x & 15;
    const float* w = W1 + o * IN_CH;
    float s = 0.0f;
    for (int k = g; k < IN_CH; k += 16) s += xrow[k] * w[k];
    #pragma unroll
    for (int m = 8; m >= 1; m >>= 1) s += __shfl_xor(s, m, 16);
    if (g == 0) h1[r * HID + o] = s + b1[o];
}

// degree count per dst (incl. self loop) + src-occurrence count over t<N_TE
__global__ void cnt_kernel(const int* __restrict__ ei, float* __restrict__ cnt,
                           int* __restrict__ srcCnt) {
    int e = blockIdx.x * blockDim.x + threadIdx.x;
    if (e >= E_TOT) return;
    int d = (e < N_EDGES) ? ei[N_EDGES + e] : (e - N_EDGES);
    atomicAdd(&cnt[d], 1.0f);
    if (e < N_TE) {
        int s = (e < N_EDGES) ? ei[e] : (e - N_EDGES);
        atomicAdd(&srcCnt[s], 1);
    }
}

// Per channel c: bitonic-sort the 1024 node values of h[:, c] (key=float as
// sortable uint, payload=node idx), emit rank[c][node] and cursor[c][rank] =
// exclusive prefix of src-multiplicities in rank order (counting-sort offsets).
template <int C>
__global__ __launch_bounds__(256) void sort_kernel(
    const float* __restrict__ h, const int* __restrict__ srcCnt,
    int* __restrict__ rank, int* __restrict__ cursor) {
    __shared__ unsigned long long a[N_NODES];
    const int c = blockIdx.x;
    const int tid = threadIdx.x;
    for (int v = tid; v < N_NODES; v += 256) {
        unsigned u = __float_as_uint(h[v * C + c]);
        u ^= (u & 0x80000000u) ? 0xFFFFFFFFu : 0x80000000u;
        a[v] = ((unsigned long long)u << 32) | (unsigned)v;
    }
    __syncthreads();
    for (int k = 2; k <= N_NODES; k <<= 1) {
        for (int j = k >> 1; j >= 1; j >>= 1) {
            for (int s = tid; s < N_NODES / 2; s += 256) {
                int i  = ((s & ~(j - 1)) << 1) | (s & (j - 1));
                int p2 = i | j;
                unsigned long long A = a[i], B = a[p2];
                bool up = ((i & k) == 0);
                if ((A > B) == up) { a[i] = B; a[p2] = A; }
            }
            __syncthreads();
        }
    }
    // ranks + exclusive prefix sum of src multiplicities in sorted order
    const int r0 = tid * 4;
    int n0 = (int)(a[r0]     & 0xFFFFFFFFu);
    int n1 = (int)(a[r0 + 1] & 0xFFFFFFFFu);
    int n2 = (int)(a[r0 + 2] & 0xFFFFFFFFu);
    int n3 = (int)(a[r0 + 3] & 0xFFFFFFFFu);
    rank[c * N_NODES + n0] = r0;
    rank[c * N_NODES + n1] = r0 + 1;
    rank[c * N_NODES + n2] = r0 + 2;
    rank[c * N_NODES + n3] = r0 + 3;
    int c0 = srcCnt[n0], c1 = srcCnt[n1], c2 = srcCnt[n2], c3 = srcCnt[n3];
    int seg = c0 + c1 + c2 + c3;
    int run = seg;
    const int lane = tid & 63, wid = tid >> 6;
    #pragma unroll
    for (int m = 1; m < 64; m <<= 1) {
        int v = __shfl_up(run, m, 64);
        if (lane >= m) run += v;
    }
    __shared__ int wsum[4];
    if (lane == 63) wsum[wid] = run;
    __syncthreads();
    int base = 0;
    for (int ww = 0; ww < wid; ++ww) base += wsum[ww];
    int excl = base + run - seg;
    cursor[c * N_NODES + r0]     = excl;
    cursor[c * N_NODES + r0 + 1] = excl + c0;
    cursor[c * N_NODES + r0 + 2] = excl + c0 + c1;
    cursor[c * N_NODES + r0 + 3] = excl + c0 + c1 + c2;
}

// Counting-sort fill: scatter each embedded point t into its y-sorted slot.
// Order inside equal-y groups is arbitrary (results order-independent).
template <int C>
__global__ void fill_kernel(const float* __restrict__ h, const int* __restrict__ ei,
                            const int* __restrict__ rank, int* __restrict__ cursor,
                            float* __restrict__ xs, float* __restrict__ ys,
                            float* __restrict__ zs) {
    int idx = blockIdx.x * blockDim.x + threadIdx.x;
    if (idx >= N_TE * C) return;
    int t = idx / C, c = idx % C;
    int s  = (t < N_EDGES)     ? ei[t]     : t - N_EDGES;
    int sn = (t + 1 < N_EDGES) ? ei[t + 1] : t + 1 - N_EDGES;
    int d  = (t < N_EDGES) ? ei[N_EDGES + t] : t - N_EDGES;
    int r = rank[c * N_NODES + s];
    int pos = atomicAdd(&cursor[c * N_NODES + r], 1);
    ys[c * SP + pos] = h[s  * C + c];
    xs[c * SP + pos] = h[d  * C + c];
    zs[c * SP + pos] = h[sn * C + c];
}

// Fused KSG per point (thread = sorted position p):
//   eps-scan: outward in sorted-y order, exact early exit (d_joint >= |dy|,
//             |dy| monotone in sorted order -> skipped j provably can't win)
//   count-scan: contiguous window {|dy| < eps}, exact same predicates as ref
//   digamma + block reduce -> tes[c]
// Self pair counted iff eps > 0 (cancels ref's -1/+1; preserves digamma(0)=-inf
// in the degenerate duplicate-triple case).
template <int C>
__global__ __launch_bounds__(256) void te_kernel(
    const float* __restrict__ xs, const float* __restrict__ ys,
    const float* __restrict__ zs, float* __restrict__ tes) {
    const int c = blockIdx.y;
    const int p = blockIdx.x * 256 + threadIdx.x;
    const float* __restrict__ X = xs + c * SP;
    const float* __restrict__ Y = ys + c * SP;
    const float* __restrict__ Z = zs + c * SP;
    float local = 0.0f;
    if (p < N_TE) {
        const float xi = X[p], yi = Y[p], zi = Z[p];
        float best = FLT_MAX;
        for (int r = p + 1; r < N_TE; ++r) {
            float dy = Y[r] - yi;                 // >= 0, monotone in r
            if (dy >= best) break;
            float d = fmaxf(fmaxf(fabsf(X[r] - xi), dy), fabsf(Z[r] - zi));
            best = fminf(best, d);
        }
        for (int l = p - 1; l >= 0; --l) {
            float dy = yi - Y[l];                 // >= 0, monotone in -l
            if (dy >= best) break;
            float d = fmaxf(fmaxf(fabsf(X[l] - xi), dy), fabsf(Z[l] - zi));
            best = fminf(best, d);
        }
        const float eps = best;
        int inc = (0.0f < eps) ? 1 : 0;
        int ny = inc, nxy = inc, nyz = inc;
        for (int r = p + 1; r < N_TE; ++r) {
            float dy = Y[r] - yi;
            if (!(dy < eps)) break;               // window end (monotone)
            ny++;
            nxy += (fabsf(X[r] - xi) < eps) ? 1 : 0;
            nyz += (fabsf(Z[r] - zi) < eps) ? 1 : 0;
        }
        for (int l = p - 1; l >= 0; --l) {
            float dy = yi - Y[l];
            if (!(dy < eps)) break;
            ny++;
            nxy += (fabsf(X[l] - xi) < eps) ? 1 : 0;
            nyz += (fabsf(Z[l] - zi) < eps) ? 1 : 0;
        }
        local = digammaf_dev((float)ny) - digammaf_dev((float)nxy)
              - digammaf_dev((float)nyz);
    }
    #pragma unroll
    for (int m = 32; m >= 1; m >>= 1) local += __shfl_xor(local, m, 64);
    __shared__ float wsum[4];
    if ((threadIdx.x & 63) == 0) wsum[threadIdx.x >> 6] = local;
    __syncthreads();
    if (threadIdx.x == 0)
        atomicAdd(&tes[c], wsum[0] + wsum[1] + wsum[2] + wsum[3]);
}

// msg = sigmoid(te_c * h[src][c]); segment-sum into sums[dst][c]
template <int C>
__global__ void agg_kernel(const float* __restrict__ h, const int* __restrict__ ei,
                           const float* __restrict__ tes_accum, float half_scale,
                           float* __restrict__ sums) {
    int idx = blockIdx.x * blockDim.x + threadIdx.x;
    if (idx >= E_TOT * C) return;
    int e = idx / C, c = idx % C;
    int s = (e < N_EDGES) ? ei[e] : (e - N_EDGES);
    int d = (e < N_EDGES) ? ei[N_EDGES + e] : (e - N_EDGES);
    float te = (-0.57721566490153286f + tes_accum[c] * (1.0f / (float)N_TE)) * half_scale;
    float xj = h[s * C + c];
    float m = 1.0f / (1.0f + expf(-te * xj));
    atomicAdd(&sums[d * C + c], m);
}

__global__ void fin1_kernel(const float* __restrict__ sums, const float* __restrict__ cnt,
                            float* __restrict__ h1a) {
    int idx = blockIdx.x * blockDim.x + threadIdx.x;
    if (idx >= N_NODES * HID) return;
    int v = idx / HID;
    float val = sums[idx] / fmaxf(cnt[v], 1.0f);
    h1a[idx] = fmaxf(val, 0.0f);
}

__global__ void gemm2_kernel(const float* __restrict__ h1a, const float* __restrict__ W2,
                             const float* __restrict__ b2, float* __restrict__ h2) {
    int idx = blockIdx.x * blockDim.x + threadIdx.x;
    if (idx >= N_NODES * OUT_CH) return;
    int v = idx / OUT_CH, o = idx % OUT_CH;
    float s = b2[o];
    #pragma unroll
    for (int k = 0; k < HID; ++k) s += h1a[v * HID + k] * W2[o * HID + k];
    h2[idx] = s;
}

__global__ void fin2_kernel(const float* __restrict__ sums2, const float* __restrict__ cnt,
                            float* __restrict__ out) {
    int v = blockIdx.x * blockDim.x + threadIdx.x;
    if (v >= N_NODES) return;
    float c = fmaxf(cnt[v], 1.0f);
    float vals[OUT_CH];
    float mx = -INFINITY;
    #pragma unroll
    for (int o = 0; o < OUT_CH; ++o) {
        vals[o] = sums2[v * OUT_CH + o] / c;
        mx = fmaxf(mx, vals[o]);
    }
    float se = 0.0f;
    #pragma unroll
    for (int o = 0; o < OUT_CH; ++o) se += expf(vals[o] - mx);
    float lse = mx + logf(se);
    #pragma unroll
    for (int o = 0; o < OUT_CH; ++o) out[v * OUT_CH + o] = vals[o] - lse;
}

extern "C" void kernel_launch(void* const* d_in, const int* in_sizes, int n_in,
                              void* d_out, int out_size, void* d_ws, size_t ws_size,
                              hipStream_t stream) {
    const float* x  = (const float*)d_in[0];
    const int*   ei = (const int*)  d_in[1];
    const float* W1 = (const float*)d_in[2];
    const float* b1 = (const float*)d_in[3];
    const float* W2 = (const float*)d_in[4];
    const float* b2 = (const float*)d_in[5];
    float* out = (float*)d_out;

    float* w = (float*)d_ws;
    size_t o = 0;
    // ---- zeroed region (atomic accumulators) ----
    float* sums1 = w + o; o += N_NODES * HID;      // 16384
    float* sums2 = w + o; o += N_NODES * OUT_CH;   // 7168
    float* cdeg  = w + o; o += N_NODES;            // 1024
    float* tes1  = w + o; o += 16;
    float* tes2  = w + o; o += 16;
    int* srcCnt  = (int*)(w + o); o += N_NODES;    // 1024 ints
    const size_t zero_elems = o;
    // ---- non-zeroed region ----
    float* h1    = w + o; o += N_NODES * HID;
    float* h1a   = w + o; o += N_NODES * HID;
    float* h2    = w + o; o += N_NODES * OUT_CH;
    float* xs1   = w + o; o += HID * SP;
    float* ys1   = w + o; o += HID * SP;
    float* zs1   = w + o; o += HID * SP;
    float* xs2   = w + o; o += OUT_CH * SP;
    float* ys2   = w + o; o += OUT_CH * SP;
    float* zs2   = w + o; o += OUT_CH * SP;
    int* rank1   = (int*)(w + o); o += HID * N_NODES;
    int* cur1    = (int*)(w + o); o += HID * N_NODES;
    int* rank2   = (int*)(w + o); o += OUT_CH * N_NODES;
    int* cur2    = (int*)(w + o); o += OUT_CH * N_NODES;

    hipMemsetAsync(d_ws, 0, zero_elems * sizeof(float), stream);

    gemm1_kernel<<<N_NODES, 256, 0, stream>>>(x, W1, b1, h1);
    cnt_kernel<<<(E_TOT + 255) / 256, 256, 0, stream>>>(ei, cdeg, srcCnt);

    // ---- layer 1 TE ----
    sort_kernel<HID><<<HID, 256, 0, stream>>>(h1, srcCnt, rank1, cur1);
    fill_kernel<HID><<<(N_TE * HID + 255) / 256, 256, 0, stream>>>(h1, ei, rank1, cur1,
                                                                   xs1, ys1, zs1);
    te_kernel<HID><<<dim3((N_TE + 255) / 256, HID), 256, 0, stream>>>(xs1, ys1, zs1, tes1);
    agg_kernel<HID><<<(E_TOT * HID + 255) / 256, 256, 0, stream>>>(h1, ei, tes1, 1.0f, sums1);
    fin1_kernel<<<(N_NODES * HID + 255) / 256, 256, 0, stream>>>(sums1, cdeg, h1a);

    // ---- layer 2 ----
    gemm2_kernel<<<(N_NODES * OUT_CH + 255) / 256, 256, 0, stream>>>(h1a, W2, b2, h2);
    sort_kernel<OUT_CH><<<OUT_CH, 256, 0, stream>>>(h2, srcCnt, rank2, cur2);
    fill_kernel<OUT_CH><<<(N_TE * OUT_CH + 255) / 256, 256, 0, stream>>>(h2, ei, rank2, cur2,
                                                                         xs2, ys2, zs2);
    te_kernel<OUT_CH><<<dim3((N_TE + 255) / 256, OUT_CH), 256, 0, stream>>>(xs2, ys2, zs2, tes2);
    agg_kernel<OUT_CH><<<(E_TOT * OUT_CH + 255) / 256, 256, 0, stream>>>(h2, ei, tes2, 0.5f, sums2);
    fin2_kernel<<<(N_NODES + 255) / 256, 256, 0, stream>>>(sums2, cdeg, out);
}

// Round 2
// 957.643 us; speedup vs baseline: 2.9643x; 2.9643x over previous
//
#include <hip/hip_runtime.h>
#include <math.h>
#include <float.h>

#define N_NODES 1024
#define IN_CH   1433
#define HID     16
#define OUT_CH  7
#define N_EDGES 4096
#define E_TOT   5120   // N_EDGES + N_NODES (self loops)
#define N_TE    5119   // embedded series length
#define SP      5120   // pitch for per-channel sorted arrays

// psi(x) for integer-valued x >= 1. Recurrence to x>=6 then asymptotic.
// digammaf_dev(0) = -inf, matching jax digamma(0) for the degenerate eps==0 case.
__device__ __forceinline__ float digammaf_dev(float x) {
    float r = 0.0f;
    while (x < 6.0f) { r -= 1.0f / x; x += 1.0f; }
    float inv  = 1.0f / x;
    float inv2 = inv * inv;
    r += logf(x) - 0.5f * inv
       - inv2 * (1.0f/12.0f - inv2 * (1.0f/120.0f - inv2 * (1.0f/252.0f)));
    return r;
}

// h1[r][o] = sum_k x[r][k] * W1[o][k] + b1[o].  One block per row.
__global__ __launch_bounds__(256) void gemm1_kernel(
    const float* __restrict__ x, const float* __restrict__ W1,
    const float* __restrict__ b1, float* __restrict__ h1) {
    __shared__ float xrow[IN_CH];
    const int r = blockIdx.x;
    const float* xr = x + (size_t)r * IN_CH;
    for (int k = threadIdx.x; k < IN_CH; k += 256) xrow[k] = xr[k];
    __syncthreads();
    const int o = threadIdx.x >> 4;
    const int g = threadIdx.x & 15;
    const float* w = W1 + o * IN_CH;
    float s = 0.0f;
    for (int k = g; k < IN_CH; k += 16) s += xrow[k] * w[k];
    #pragma unroll
    for (int m = 8; m >= 1; m >>= 1) s += __shfl_xor(s, m, 16);
    if (g == 0) h1[r * HID + o] = s + b1[o];
}

// degree count per dst (incl. self loop) + src-occurrence count over t<N_TE
__global__ void cnt_kernel(const int* __restrict__ ei, float* __restrict__ cnt,
                           int* __restrict__ srcCnt) {
    int e = blockIdx.x * blockDim.x + threadIdx.x;
    if (e >= E_TOT) return;
    int d = (e < N_EDGES) ? ei[N_EDGES + e] : (e - N_EDGES);
    atomicAdd(&cnt[d], 1.0f);
    if (e < N_TE) {
        int s = (e < N_EDGES) ? ei[e] : (e - N_EDGES);
        atomicAdd(&srcCnt[s], 1);
    }
}

// Per channel c: bitonic-sort the 1024 node values of h[:, c] (key=float as
// sortable uint, payload=node idx), emit rank[c][node] and cursor[c][rank] =
// exclusive prefix of src-multiplicities in rank order (counting-sort offsets).
template <int C>
__global__ __launch_bounds__(256) void sort_kernel(
    const float* __restrict__ h, const int* __restrict__ srcCnt,
    int* __restrict__ rank, int* __restrict__ cursor) {
    __shared__ unsigned long long a[N_NODES];
    const int c = blockIdx.x;
    const int tid = threadIdx.x;
    for (int v = tid; v < N_NODES; v += 256) {
        unsigned u = __float_as_uint(h[v * C + c]);
        u ^= (u & 0x80000000u) ? 0xFFFFFFFFu : 0x80000000u;
        a[v] = ((unsigned long long)u << 32) | (unsigned)v;
    }
    __syncthreads();
    for (int k = 2; k <= N_NODES; k <<= 1) {
        for (int j = k >> 1; j >= 1; j >>= 1) {
            for (int s = tid; s < N_NODES / 2; s += 256) {
                int i  = ((s & ~(j - 1)) << 1) | (s & (j - 1));
                int p2 = i | j;
                unsigned long long A = a[i], B = a[p2];
                bool up = ((i & k) == 0);
                if ((A > B) == up) { a[i] = B; a[p2] = A; }
            }
            __syncthreads();
        }
    }
    // ranks + exclusive prefix sum of src multiplicities in sorted order
    const int r0 = tid * 4;
    int n0 = (int)(a[r0]     & 0xFFFFFFFFu);
    int n1 = (int)(a[r0 + 1] & 0xFFFFFFFFu);
    int n2 = (int)(a[r0 + 2] & 0xFFFFFFFFu);
    int n3 = (int)(a[r0 + 3] & 0xFFFFFFFFu);
    rank[c * N_NODES + n0] = r0;
    rank[c * N_NODES + n1] = r0 + 1;
    rank[c * N_NODES + n2] = r0 + 2;
    rank[c * N_NODES + n3] = r0 + 3;
    int c0 = srcCnt[n0], c1 = srcCnt[n1], c2 = srcCnt[n2], c3 = srcCnt[n3];
    int seg = c0 + c1 + c2 + c3;
    int run = seg;
    const int lane = tid & 63, wid = tid >> 6;
    #pragma unroll
    for (int m = 1; m < 64; m <<= 1) {
        int v = __shfl_up(run, m, 64);
        if (lane >= m) run += v;
    }
    __shared__ int wsum[4];
    if (lane == 63) wsum[wid] = run;
    __syncthreads();
    int base = 0;
    for (int ww = 0; ww < wid; ++ww) base += wsum[ww];
    int excl = base + run - seg;
    cursor[c * N_NODES + r0]     = excl;
    cursor[c * N_NODES + r0 + 1] = excl + c0;
    cursor[c * N_NODES + r0 + 2] = excl + c0 + c1;
    cursor[c * N_NODES + r0 + 3] = excl + c0 + c1 + c2;
}

// Counting-sort fill: scatter each embedded point t into its y-sorted slot.
// Order inside equal-y groups is arbitrary (results order-independent).
template <int C>
__global__ void fill_kernel(const float* __restrict__ h, const int* __restrict__ ei,
                            const int* __restrict__ rank, int* __restrict__ cursor,
                            float* __restrict__ xs, float* __restrict__ ys,
                            float* __restrict__ zs) {
    int idx = blockIdx.x * blockDim.x + threadIdx.x;
    if (idx >= N_TE * C) return;
    int t = idx / C, c = idx % C;
    int s  = (t < N_EDGES)     ? ei[t]     : t - N_EDGES;
    int sn = (t + 1 < N_EDGES) ? ei[t + 1] : t + 1 - N_EDGES;
    int d  = (t < N_EDGES) ? ei[N_EDGES + t] : t - N_EDGES;
    int r = rank[c * N_NODES + s];
    int pos = atomicAdd(&cursor[c * N_NODES + r], 1);
    ys[c * SP + pos] = h[s  * C + c];
    xs[c * SP + pos] = h[d  * C + c];
    zs[c * SP + pos] = h[sn * C + c];
}

// ---- per-element helpers for the chunked scans ----
// eps phase: processing overshoot is exact-safe (d >= |dy| >= best for any
// element at/after the true stop), only j==p needs masking (d would be 0).
#define TE_EPS1(jj, yv, xv, zv)                                              \
    {                                                                        \
        float d_ = fmaxf(fmaxf(fabsf((xv) - xi), fabsf((yv) - yi)),          \
                         fabsf((zv) - zi));                                  \
        d_ = ((jj) == p) ? FLT_MAX : d_;                                     \
        best = fminf(best, d_);                                              \
    }
#define TE_EPS4(bj, y4, x4, z4)                                              \
    TE_EPS1((bj) + 0, (y4).x, (x4).x, (z4).x)                                \
    TE_EPS1((bj) + 1, (y4).y, (x4).y, (z4).y)                                \
    TE_EPS1((bj) + 2, (y4).z, (x4).z, (z4).z)                                \
    TE_EPS1((bj) + 3, (y4).w, (x4).w, (z4).w)

// count phase: exact per-element predicates; side condition prevents
// double-count between the two directional scans.
#define TE_CNT1(cond, yv, xv, zv)                                            \
    {                                                                        \
        int w_ = (int)(cond) & (int)(fabsf((yv) - yi) < eps);                \
        ny  += w_;                                                           \
        nxy += w_ & (int)(fabsf((xv) - xi) < eps);                           \
        nyz += w_ & (int)(fabsf((zv) - zi) < eps);                           \
    }
#define TE_CNT4R(bj, y4, x4, z4)                                             \
    TE_CNT1((bj) + 0 > p, (y4).x, (x4).x, (z4).x)                            \
    TE_CNT1((bj) + 1 > p, (y4).y, (x4).y, (z4).y)                            \
    TE_CNT1((bj) + 2 > p, (y4).z, (x4).z, (z4).z)                            \
    TE_CNT1((bj) + 3 > p, (y4).w, (x4).w, (z4).w)
#define TE_CNT4L(bj, y4, x4, z4)                                             \
    TE_CNT1((bj) + 0 < p, (y4).x, (x4).x, (z4).x)                            \
    TE_CNT1((bj) + 1 < p, (y4).y, (x4).y, (z4).y)                            \
    TE_CNT1((bj) + 2 < p, (y4).z, (x4).z, (z4).z)                            \
    TE_CNT1((bj) + 3 < p, (y4).w, (x4).w, (z4).w)

#define TE_LOAD16(arr)                                                       \
    const float4* py4 = (const float4*)(Ys + LOFF + b);                      \
    const float4* px4 = (const float4*)(Xs + LOFF + b);                      \
    const float4* pz4 = (const float4*)(Zs + LOFF + b);                      \
    float4 y0 = py4[0], y1 = py4[1], y2 = py4[2], y3 = py4[3];               \
    float4 x0 = px4[0], x1 = px4[1], x2 = px4[2], x3 = px4[3];               \
    float4 z0 = pz4[0], z1 = pz4[1], z2 = pz4[2], z3 = pz4[3];

// Fused KSG per point (thread = sorted position p), LDS-staged, chunked.
//   eps-scan: outward in sorted-y order; chunk of 16 processed branch-free;
//             break once the chunk's extreme dy >= best (monotone => all
//             further elements provably can't improve the min).
//   count-scan: same chunking; per-element window predicate |dy|<eps is exact.
// Self pair counted iff eps > 0 (cancels ref's -1/+1; preserves digamma(0)=-inf
// in the degenerate duplicate-triple case). +/-FLT_MAX padding guarantees
// termination and contributes nothing.
template <int C>
__global__ __launch_bounds__(256) void te_kernel(
    const float* __restrict__ xs, const float* __restrict__ ys,
    const float* __restrict__ zs, float* __restrict__ tes) {
    constexpr int LOFF = 16;
    constexpr int LSZ  = LOFF + SP + 16;   // 5152 floats per array
    __shared__ __align__(16) float Xs[LSZ];
    __shared__ __align__(16) float Ys[LSZ];
    __shared__ __align__(16) float Zs[LSZ];
    const int c = blockIdx.y;
    const int tid = threadIdx.x;
    for (int s = tid; s < LSZ; s += 256) {
        int g = s - LOFF;
        bool v = (g >= 0) && (g < N_TE);
        float pad = (g < 0) ? -FLT_MAX : FLT_MAX;
        Xs[s] = v ? xs[c * SP + g] : pad;
        Ys[s] = v ? ys[c * SP + g] : pad;
        Zs[s] = v ? zs[c * SP + g] : pad;
    }
    __syncthreads();
    const int p = blockIdx.x * 256 + tid;
    float local = 0.0f;
    if (p < N_TE) {
        const float xi = Xs[LOFF + p], yi = Ys[LOFF + p], zi = Zs[LOFF + p];
        float best = FLT_MAX;
        // ---- eps: right (ascending y) ----
        for (int b = (p + 1) & ~15; ; b += 16) {
            TE_LOAD16()
            TE_EPS4(b, y0, x0, z0)
            TE_EPS4(b + 4, y1, x1, z1)
            TE_EPS4(b + 8, y2, x2, z2)
            TE_EPS4(b + 12, y3, x3, z3)
            if (y3.w - yi >= best) break;   // monotone lower bound on all later d
        }
        // ---- eps: left (descending y) ----
        for (int b = (p - 1) & ~15; ; b -= 16) {
            TE_LOAD16()
            TE_EPS4(b, y0, x0, z0)
            TE_EPS4(b + 4, y1, x1, z1)
            TE_EPS4(b + 8, y2, x2, z2)
            TE_EPS4(b + 12, y3, x3, z3)
            if (yi - y0.x >= best) break;
        }
        const float eps = best;
        int inc = (0.0f < eps) ? 1 : 0;
        int ny = inc, nxy = inc, nyz = inc;
        // ---- count: right ----
        for (int b = (p + 1) & ~15; ; b += 16) {
            TE_LOAD16()
            TE_CNT4R(b, y0, x0, z0)
            TE_CNT4R(b + 4, y1, x1, z1)
            TE_CNT4R(b + 8, y2, x2, z2)
            TE_CNT4R(b + 12, y3, x3, z3)
            if (y3.w - yi >= eps) break;    // window is contiguous (monotone)
        }
        // ---- count: left ----
        for (int b = (p - 1) & ~15; ; b -= 16) {
            TE_LOAD16()
            TE_CNT4L(b, y0, x0, z0)
            TE_CNT4L(b + 4, y1, x1, z1)
            TE_CNT4L(b + 8, y2, x2, z2)
            TE_CNT4L(b + 12, y3, x3, z3)
            if (yi - y0.x >= eps) break;
        }
        local = digammaf_dev((float)ny) - digammaf_dev((float)nxy)
              - digammaf_dev((float)nyz);
    }
    #pragma unroll
    for (int m = 32; m >= 1; m >>= 1) local += __shfl_xor(local, m, 64);
    __shared__ float wsum[4];
    if ((threadIdx.x & 63) == 0) wsum[threadIdx.x >> 6] = local;
    __syncthreads();
    if (threadIdx.x == 0)
        atomicAdd(&tes[c], wsum[0] + wsum[1] + wsum[2] + wsum[3]);
}

// msg = sigmoid(te_c * h[src][c]); segment-sum into sums[dst][c]
template <int C>
__global__ void agg_kernel(const float* __restrict__ h, const int* __restrict__ ei,
                           const float* __restrict__ tes_accum, float half_scale,
                           float* __restrict__ sums) {
    int idx = blockIdx.x * blockDim.x + threadIdx.x;
    if (idx >= E_TOT * C) return;
    int e = idx / C, c = idx % C;
    int s = (e < N_EDGES) ? ei[e] : (e - N_EDGES);
    int d = (e < N_EDGES) ? ei[N_EDGES + e] : (e - N_EDGES);
    float te = (-0.57721566490153286f + tes_accum[c] * (1.0f / (float)N_TE)) * half_scale;
    float xj = h[s * C + c];
    float m = 1.0f / (1.0f + expf(-te * xj));
    atomicAdd(&sums[d * C + c], m);
}

__global__ void fin1_kernel(const float* __restrict__ sums, const float* __restrict__ cnt,
                            float* __restrict__ h1a) {
    int idx = blockIdx.x * blockDim.x + threadIdx.x;
    if (idx >= N_NODES * HID) return;
    int v = idx / HID;
    float val = sums[idx] / fmaxf(cnt[v], 1.0f);
    h1a[idx] = fmaxf(val, 0.0f);
}

__global__ void gemm2_kernel(const float* __restrict__ h1a, const float* __restrict__ W2,
                             const float* __restrict__ b2, float* __restrict__ h2) {
    int idx = blockIdx.x * blockDim.x + threadIdx.x;
    if (idx >= N_NODES * OUT_CH) return;
    int v = idx / OUT_CH, o = idx % OUT_CH;
    float s = b2[o];
    #pragma unroll
    for (int k = 0; k < HID; ++k) s += h1a[v * HID + k] * W2[o * HID + k];
    h2[idx] = s;
}

__global__ void fin2_kernel(const float* __restrict__ sums2, const float* __restrict__ cnt,
                            float* __restrict__ out) {
    int v = blockIdx.x * blockDim.x + threadIdx.x;
    if (v >= N_NODES) return;
    float c = fmaxf(cnt[v], 1.0f);
    float vals[OUT_CH];
    float mx = -INFINITY;
    #pragma unroll
    for (int o = 0; o < OUT_CH; ++o) {
        vals[o] = sums2[v * OUT_CH + o] / c;
        mx = fmaxf(mx, vals[o]);
    }
    float se = 0.0f;
    #pragma unroll
    for (int o = 0; o < OUT_CH; ++o) se += expf(vals[o] - mx);
    float lse = mx + logf(se);
    #pragma unroll
    for (int o = 0; o < OUT_CH; ++o) out[v * OUT_CH + o] = vals[o] - lse;
}

extern "C" void kernel_launch(void* const* d_in, const int* in_sizes, int n_in,
                              void* d_out, int out_size, void* d_ws, size_t ws_size,
                              hipStream_t stream) {
    const float* x  = (const float*)d_in[0];
    const int*   ei = (const int*)  d_in[1];
    const float* W1 = (const float*)d_in[2];
    const float* b1 = (const float*)d_in[3];
    const float* W2 = (const float*)d_in[4];
    const float* b2 = (const float*)d_in[5];
    float* out = (float*)d_out;

    float* w = (float*)d_ws;
    size_t o = 0;
    // ---- zeroed region (atomic accumulators) ----
    float* sums1 = w + o; o += N_NODES * HID;      // 16384
    float* sums2 = w + o; o += N_NODES * OUT_CH;   // 7168
    float* cdeg  = w + o; o += N_NODES;            // 1024
    float* tes1  = w + o; o += 16;
    float* tes2  = w + o; o += 16;
    int* srcCnt  = (int*)(w + o); o += N_NODES;    // 1024 ints
    const size_t zero_elems = o;
    // ---- non-zeroed region ----
    float* h1    = w + o; o += N_NODES * HID;
    float* h1a   = w + o; o += N_NODES * HID;
    float* h2    = w + o; o += N_NODES * OUT_CH;
    float* xs1   = w + o; o += HID * SP;
    float* ys1   = w + o; o += HID * SP;
    float* zs1   = w + o; o += HID * SP;
    float* xs2   = w + o; o += OUT_CH * SP;
    float* ys2   = w + o; o += OUT_CH * SP;
    float* zs2   = w + o; o += OUT_CH * SP;
    int* rank1   = (int*)(w + o); o += HID * N_NODES;
    int* cur1    = (int*)(w + o); o += HID * N_NODES;
    int* rank2   = (int*)(w + o); o += OUT_CH * N_NODES;
    int* cur2    = (int*)(w + o); o += OUT_CH * N_NODES;

    hipMemsetAsync(d_ws, 0, zero_elems * sizeof(float), stream);

    gemm1_kernel<<<N_NODES, 256, 0, stream>>>(x, W1, b1, h1);
    cnt_kernel<<<(E_TOT + 255) / 256, 256, 0, stream>>>(ei, cdeg, srcCnt);

    // ---- layer 1 TE ----
    sort_kernel<HID><<<HID, 256, 0, stream>>>(h1, srcCnt, rank1, cur1);
    fill_kernel<HID><<<(N_TE * HID + 255) / 256, 256, 0, stream>>>(h1, ei, rank1, cur1,
                                                                   xs1, ys1, zs1);
    te_kernel<HID><<<dim3((N_TE + 255) / 256, HID), 256, 0, stream>>>(xs1, ys1, zs1, tes1);
    agg_kernel<HID><<<(E_TOT * HID + 255) / 256, 256, 0, stream>>>(h1, ei, tes1, 1.0f, sums1);
    fin1_kernel<<<(N_NODES * HID + 255) / 256, 256, 0, stream>>>(sums1, cdeg, h1a);

    // ---- layer 2 ----
    gemm2_kernel<<<(N_NODES * OUT_CH + 255) / 256, 256, 0, stream>>>(h1a, W2, b2, h2);
    sort_kernel<OUT_CH><<<OUT_CH, 256, 0, stream>>>(h2, srcCnt, rank2, cur2);
    fill_kernel<OUT_CH><<<(N_TE * OUT_CH + 255) / 256, 256, 0, stream>>>(h2, ei, rank2, cur2,
                                                                         xs2, ys2, zs2);
    te_kernel<OUT_CH><<<dim3((N_TE + 255) / 256, OUT_CH), 256, 0, stream>>>(xs2, ys2, zs2, tes2);
    agg_kernel<OUT_CH><<<(E_TOT * OUT_CH + 255) / 256, 256, 0, stream>>>(h2, ei, tes2, 0.5f, sums2);
    fin2_kernel<<<(N_NODES + 255) / 256, 256, 0, stream>>>(sums2, cdeg, out);
}

// Round 3
// 338.661 us; speedup vs baseline: 8.3824x; 2.8277x over previous
//
#include <hip/hip_runtime.h>
#include <math.h>
#include <float.h>

#define N_NODES 1024
#define IN_CH   1433
#define HID     16
#define OUT_CH  7
#define N_EDGES 4096
#define E_TOT   5120   // N_EDGES + N_NODES (self loops)
#define N_TE    5119   // embedded series length (valid sorted slots 0..5118)
#define SP      5120   // pitch for per-channel sorted arrays

// psi(x) for integer-valued x >= 1. Recurrence to x>=6 then asymptotic.
// digammaf_dev(0) = -inf, matching jax digamma(0) for the degenerate eps==0 case.
__device__ __forceinline__ float digammaf_dev(float x) {
    float r = 0.0f;
    while (x < 6.0f) { r -= 1.0f / x; x += 1.0f; }
    float inv  = 1.0f / x;
    float inv2 = inv * inv;
    r += logf(x) - 0.5f * inv
       - inv2 * (1.0f/12.0f - inv2 * (1.0f/120.0f - inv2 * (1.0f/252.0f)));
    return r;
}

// h1[r][o] = sum_k x[r][k] * W1[o][k] + b1[o].  One block per row.
__global__ __launch_bounds__(256) void gemm1_kernel(
    const float* __restrict__ x, const float* __restrict__ W1,
    const float* __restrict__ b1, float* __restrict__ h1) {
    __shared__ float xrow[IN_CH];
    const int r = blockIdx.x;
    const float* xr = x + (size_t)r * IN_CH;
    for (int k = threadIdx.x; k < IN_CH; k += 256) xrow[k] = xr[k];
    __syncthreads();
    const int o = threadIdx.x >> 4;
    const int g = threadIdx.x & 15;
    const float* w = W1 + o * IN_CH;
    float s = 0.0f;
    for (int k = g; k < IN_CH; k += 16) s += xrow[k] * w[k];
    #pragma unroll
    for (int m = 8; m >= 1; m >>= 1) s += __shfl_xor(s, m, 16);
    if (g == 0) h1[r * HID + o] = s + b1[o];
}

// degree count per dst (incl. self loop) + src-occurrence count over t<N_TE
__global__ void cnt_kernel(const int* __restrict__ ei, float* __restrict__ cnt,
                           int* __restrict__ srcCnt) {
    int e = blockIdx.x * blockDim.x + threadIdx.x;
    if (e >= E_TOT) return;
    int d = (e < N_EDGES) ? ei[N_EDGES + e] : (e - N_EDGES);
    atomicAdd(&cnt[d], 1.0f);
    if (e < N_TE) {
        int s = (e < N_EDGES) ? ei[e] : (e - N_EDGES);
        atomicAdd(&srcCnt[s], 1);
    }
}

// Per channel c: bitonic-sort the 1024 node values of h[:, c] (key=float as
// sortable uint, payload=node idx), emit rank[c][node] and cursor[c][rank] =
// exclusive prefix of src-multiplicities in rank order (counting-sort offsets).
template <int C>
__global__ __launch_bounds__(256) void sort_kernel(
    const float* __restrict__ h, const int* __restrict__ srcCnt,
    int* __restrict__ rank, int* __restrict__ cursor) {
    __shared__ unsigned long long a[N_NODES];
    const int c = blockIdx.x;
    const int tid = threadIdx.x;
    for (int v = tid; v < N_NODES; v += 256) {
        unsigned u = __float_as_uint(h[v * C + c]);
        u ^= (u & 0x80000000u) ? 0xFFFFFFFFu : 0x80000000u;
        a[v] = ((unsigned long long)u << 32) | (unsigned)v;
    }
    __syncthreads();
    for (int k = 2; k <= N_NODES; k <<= 1) {
        for (int j = k >> 1; j >= 1; j >>= 1) {
            for (int s = tid; s < N_NODES / 2; s += 256) {
                int i  = ((s & ~(j - 1)) << 1) | (s & (j - 1));
                int p2 = i | j;
                unsigned long long A = a[i], B = a[p2];
                bool up = ((i & k) == 0);
                if ((A > B) == up) { a[i] = B; a[p2] = A; }
            }
            __syncthreads();
        }
    }
    // ranks + exclusive prefix sum of src multiplicities in sorted order
    const int r0 = tid * 4;
    int n0 = (int)(a[r0]     & 0xFFFFFFFFu);
    int n1 = (int)(a[r0 + 1] & 0xFFFFFFFFu);
    int n2 = (int)(a[r0 + 2] & 0xFFFFFFFFu);
    int n3 = (int)(a[r0 + 3] & 0xFFFFFFFFu);
    rank[c * N_NODES + n0] = r0;
    rank[c * N_NODES + n1] = r0 + 1;
    rank[c * N_NODES + n2] = r0 + 2;
    rank[c * N_NODES + n3] = r0 + 3;
    int c0 = srcCnt[n0], c1 = srcCnt[n1], c2 = srcCnt[n2], c3 = srcCnt[n3];
    int seg = c0 + c1 + c2 + c3;
    int run = seg;
    const int lane = tid & 63, wid = tid >> 6;
    #pragma unroll
    for (int m = 1; m < 64; m <<= 1) {
        int v = __shfl_up(run, m, 64);
        if (lane >= m) run += v;
    }
    __shared__ int wsum[4];
    if (lane == 63) wsum[wid] = run;
    __syncthreads();
    int base = 0;
    for (int ww = 0; ww < wid; ++ww) base += wsum[ww];
    int excl = base + run - seg;
    cursor[c * N_NODES + r0]     = excl;
    cursor[c * N_NODES + r0 + 1] = excl + c0;
    cursor[c * N_NODES + r0 + 2] = excl + c0 + c1;
    cursor[c * N_NODES + r0 + 3] = excl + c0 + c1 + c2;
}

// Counting-sort fill: scatter each embedded point t into its y-sorted slot.
// Order inside equal-y groups is arbitrary (results order-independent).
template <int C>
__global__ void fill_kernel(const float* __restrict__ h, const int* __restrict__ ei,
                            const int* __restrict__ rank, int* __restrict__ cursor,
                            float* __restrict__ xs, float* __restrict__ ys,
                            float* __restrict__ zs) {
    int idx = blockIdx.x * blockDim.x + threadIdx.x;
    if (idx >= N_TE * C) return;
    int t = idx / C, c = idx % C;
    int s  = (t < N_EDGES)     ? ei[t]     : t - N_EDGES;
    int sn = (t + 1 < N_EDGES) ? ei[t + 1] : t + 1 - N_EDGES;
    int d  = (t < N_EDGES) ? ei[N_EDGES + t] : t - N_EDGES;
    int r = rank[c * N_NODES + s];
    int pos = atomicAdd(&cursor[c * N_NODES + r], 1);
    ys[c * SP + pos] = h[s  * C + c];
    xs[c * SP + pos] = h[d  * C + c];
    zs[c * SP + pos] = h[sn * C + c];
}

// Fused KSG: 16-lane group per point p (sorted position).  Each round the
// group covers 64 contiguous elements (one float4 of x/y/z per lane) plus a
// uniform boundary-y read; monotone break conditions as before.
//   eps phase:   min over processed j!=p is exact-safe under overshoot
//                (d >= |dy| >= boundary dy for any skipped j).
//   count phase: exact per-element window predicates; j>p / j<p side masks
//                partition j!=p across the two directional scans.
// Self pair counted iff eps > 0 (cancels ref's -1/+1; preserves
// digamma(0) = -inf in the degenerate duplicate-triple case).
template <int C>
__global__ __launch_bounds__(256) void te_kernel(
    const float* __restrict__ xs, const float* __restrict__ ys,
    const float* __restrict__ zs, float* __restrict__ tes) {
    constexpr int LOFF = 64;            // left pad (-FLT_MAX)
    constexpr int LSZ  = LOFF + SP;     // 5184 floats per array
    __shared__ __align__(16) float Xs[LSZ];
    __shared__ __align__(16) float Ys[LSZ];
    __shared__ __align__(16) float Zs[LSZ];
    const int c = blockIdx.y;
    const int tid = threadIdx.x;
    {
        const float4* gx4 = (const float4*)(xs + (size_t)c * SP);
        const float4* gy4 = (const float4*)(ys + (size_t)c * SP);
        const float4* gz4 = (const float4*)(zs + (size_t)c * SP);
        float4* lx4 = (float4*)(Xs + LOFF);
        float4* ly4 = (float4*)(Ys + LOFF);
        float4* lz4 = (float4*)(Zs + LOFF);
        for (int t = tid; t < SP / 4; t += 256) {
            lx4[t] = gx4[t]; ly4[t] = gy4[t]; lz4[t] = gz4[t];
        }
        if (tid < LOFF) {  // left pad
            Xs[tid] = -FLT_MAX; Ys[tid] = -FLT_MAX; Zs[tid] = -FLT_MAX;
        }
    }
    __syncthreads();
    if (tid == 0) {  // right sentinel at sorted slot N_TE (was staged garbage)
        Xs[LOFF + N_TE] = FLT_MAX; Ys[LOFF + N_TE] = FLT_MAX; Zs[LOFF + N_TE] = FLT_MAX;
    }
    __syncthreads();

    const int g = tid >> 4, l = tid & 15;
    const int p = blockIdx.x * 16 + g;
    float local = 0.0f;
    if (p < N_TE) {
        const float xi = Xs[LOFF + p], yi = Ys[LOFF + p], zi = Zs[LOFF + p];
        const int base = p & ~63;
        const int lo = 4 * l;
        float best = FLT_MAX;
        // ---- eps: right/up (includes base block, j==p masked) ----
        for (int b = base; ; b += 64) {
            const int j0 = b + lo;
            const float4 xv = *(const float4*)(Xs + LOFF + j0);
            const float4 yv = *(const float4*)(Ys + LOFF + j0);
            const float4 zv = *(const float4*)(Zs + LOFF + j0);
            const float yB = Ys[LOFF + b + 63];       // uniform broadcast
            float d0 = fmaxf(fmaxf(fabsf(xv.x - xi), fabsf(yv.x - yi)), fabsf(zv.x - zi));
            float d1 = fmaxf(fmaxf(fabsf(xv.y - xi), fabsf(yv.y - yi)), fabsf(zv.y - zi));
            float d2 = fmaxf(fmaxf(fabsf(xv.z - xi), fabsf(yv.z - yi)), fabsf(zv.z - zi));
            float d3 = fmaxf(fmaxf(fabsf(xv.w - xi), fabsf(yv.w - yi)), fabsf(zv.w - zi));
            d0 = (j0     == p) ? FLT_MAX : d0;
            d1 = (j0 + 1 == p) ? FLT_MAX : d1;
            d2 = (j0 + 2 == p) ? FLT_MAX : d2;
            d3 = (j0 + 3 == p) ? FLT_MAX : d3;
            best = fminf(best, fminf(fminf(d0, d1), fminf(d2, d3)));
            #pragma unroll
            for (int m = 1; m < 16; m <<= 1) best = fminf(best, __shfl_xor(best, m, 16));
            if (yB - yi >= best) break;   // all later j have dy >= yB - yi
        }
        // ---- eps: left/down (strictly below base; no j==p possible) ----
        for (int b = base - 64; ; b -= 64) {
            const int j0 = b + lo;
            const float4 xv = *(const float4*)(Xs + LOFF + j0);
            const float4 yv = *(const float4*)(Ys + LOFF + j0);
            const float4 zv = *(const float4*)(Zs + LOFF + j0);
            const float yB = Ys[LOFF + b];            // uniform broadcast
            float d0 = fmaxf(fmaxf(fabsf(xv.x - xi), fabsf(yv.x - yi)), fabsf(zv.x - zi));
            float d1 = fmaxf(fmaxf(fabsf(xv.y - xi), fabsf(yv.y - yi)), fabsf(zv.y - zi));
            float d2 = fmaxf(fmaxf(fabsf(xv.z - xi), fabsf(yv.z - yi)), fabsf(zv.z - zi));
            float d3 = fmaxf(fmaxf(fabsf(xv.w - xi), fabsf(yv.w - yi)), fabsf(zv.w - zi));
            best = fminf(best, fminf(fminf(d0, d1), fminf(d2, d3)));
            #pragma unroll
            for (int m = 1; m < 16; m <<= 1) best = fminf(best, __shfl_xor(best, m, 16));
            if (yi - yB >= best) break;   // all lower j have dy >= yi - yB
        }
        const float eps = best;
        int inc = (l == 0 && 0.0f < eps) ? 1 : 0;
        int ny = inc, nxy = inc, nyz = inc;
        // ---- count: right (j > p) ----
        for (int b = base; ; b += 64) {
            const int j0 = b + lo;
            const float4 xv = *(const float4*)(Xs + LOFF + j0);
            const float4 yv = *(const float4*)(Ys + LOFF + j0);
            const float4 zv = *(const float4*)(Zs + LOFF + j0);
            const float yB = Ys[LOFF + b + 63];
            int w0 = (int)(j0     > p) & (int)(fabsf(yv.x - yi) < eps);
            int w1 = (int)(j0 + 1 > p) & (int)(fabsf(yv.y - yi) < eps);
            int w2 = (int)(j0 + 2 > p) & (int)(fabsf(yv.z - yi) < eps);
            int w3 = (int)(j0 + 3 > p) & (int)(fabsf(yv.w - yi) < eps);
            ny  += w0 + w1 + w2 + w3;
            nxy += (w0 & (int)(fabsf(xv.x - xi) < eps)) + (w1 & (int)(fabsf(xv.y - xi) < eps))
                 + (w2 & (int)(fabsf(xv.z - xi) < eps)) + (w3 & (int)(fabsf(xv.w - xi) < eps));
            nyz += (w0 & (int)(fabsf(zv.x - zi) < eps)) + (w1 & (int)(fabsf(zv.y - zi) < eps))
                 + (w2 & (int)(fabsf(zv.z - zi) < eps)) + (w3 & (int)(fabsf(zv.w - zi) < eps));
            if (yB - yi >= eps) break;    // window contiguous in sorted y
        }
        // ---- count: left (j < p; includes base block) ----
        for (int b = base; ; b -= 64) {
            const int j0 = b + lo;
            const float4 xv = *(const float4*)(Xs + LOFF + j0);
            const float4 yv = *(const float4*)(Ys + LOFF + j0);
            const float4 zv = *(const float4*)(Zs + LOFF + j0);
            const float yB = Ys[LOFF + b];
            int w0 = (int)(j0     < p) & (int)(fabsf(yv.x - yi) < eps);
            int w1 = (int)(j0 + 1 < p) & (int)(fabsf(yv.y - yi) < eps);
            int w2 = (int)(j0 + 2 < p) & (int)(fabsf(yv.z - yi) < eps);
            int w3 = (int)(j0 + 3 < p) & (int)(fabsf(yv.w - yi) < eps);
            ny  += w0 + w1 + w2 + w3;
            nxy += (w0 & (int)(fabsf(xv.x - xi) < eps)) + (w1 & (int)(fabsf(xv.y - xi) < eps))
                 + (w2 & (int)(fabsf(xv.z - xi) < eps)) + (w3 & (int)(fabsf(xv.w - xi) < eps));
            nyz += (w0 & (int)(fabsf(zv.x - zi) < eps)) + (w1 & (int)(fabsf(zv.y - zi) < eps))
                 + (w2 & (int)(fabsf(zv.z - zi) < eps)) + (w3 & (int)(fabsf(zv.w - zi) < eps));
            if (yi - yB >= eps) break;
        }
        // ---- group reduce: ny,nxy packed (each <= 5120 < 8192), nyz separate
        int pack = (ny << 13) | nxy;
        #pragma unroll
        for (int m = 1; m < 16; m <<= 1) {
            pack += __shfl_xor(pack, m, 16);
            nyz  += __shfl_xor(nyz, m, 16);
        }
        if (l == 0) {
            ny  = pack >> 13;
            nxy = pack & 8191;
            local = digammaf_dev((float)ny) - digammaf_dev((float)nxy)
                  - digammaf_dev((float)nyz);
        }
    }
    #pragma unroll
    for (int m = 32; m >= 1; m >>= 1) local += __shfl_xor(local, m, 64);
    __shared__ float wsum[4];
    if ((threadIdx.x & 63) == 0) wsum[threadIdx.x >> 6] = local;
    __syncthreads();
    if (threadIdx.x == 0)
        atomicAdd(&tes[c], wsum[0] + wsum[1] + wsum[2] + wsum[3]);
}

// msg = sigmoid(te_c * h[src][c]); segment-sum into sums[dst][c]
template <int C>
__global__ void agg_kernel(const float* __restrict__ h, const int* __restrict__ ei,
                           const float* __restrict__ tes_accum, float half_scale,
                           float* __restrict__ sums) {
    int idx = blockIdx.x * blockDim.x + threadIdx.x;
    if (idx >= E_TOT * C) return;
    int e = idx / C, c = idx % C;
    int s = (e < N_EDGES) ? ei[e] : (e - N_EDGES);
    int d = (e < N_EDGES) ? ei[N_EDGES + e] : (e - N_EDGES);
    float te = (-0.57721566490153286f + tes_accum[c] * (1.0f / (float)N_TE)) * half_scale;
    float xj = h[s * C + c];
    float m = 1.0f / (1.0f + expf(-te * xj));
    atomicAdd(&sums[d * C + c], m);
}

__global__ void fin1_kernel(const float* __restrict__ sums, const float* __restrict__ cnt,
                            float* __restrict__ h1a) {
    int idx = blockIdx.x * blockDim.x + threadIdx.x;
    if (idx >= N_NODES * HID) return;
    int v = idx / HID;
    float val = sums[idx] / fmaxf(cnt[v], 1.0f);
    h1a[idx] = fmaxf(val, 0.0f);
}

__global__ void gemm2_kernel(const float* __restrict__ h1a, const float* __restrict__ W2,
                             const float* __restrict__ b2, float* __restrict__ h2) {
    int idx = blockIdx.x * blockDim.x + threadIdx.x;
    if (idx >= N_NODES * OUT_CH) return;
    int v = idx / OUT_CH, o = idx % OUT_CH;
    float s = b2[o];
    #pragma unroll
    for (int k = 0; k < HID; ++k) s += h1a[v * HID + k] * W2[o * HID + k];
    h2[idx] = s;
}

__global__ void fin2_kernel(const float* __restrict__ sums2, const float* __restrict__ cnt,
                            float* __restrict__ out) {
    int v = blockIdx.x * blockDim.x + threadIdx.x;
    if (v >= N_NODES) return;
    float c = fmaxf(cnt[v], 1.0f);
    float vals[OUT_CH];
    float mx = -INFINITY;
    #pragma unroll
    for (int o = 0; o < OUT_CH; ++o) {
        vals[o] = sums2[v * OUT_CH + o] / c;
        mx = fmaxf(mx, vals[o]);
    }
    float se = 0.0f;
    #pragma unroll
    for (int o = 0; o < OUT_CH; ++o) se += expf(vals[o] - mx);
    float lse = mx + logf(se);
    #pragma unroll
    for (int o = 0; o < OUT_CH; ++o) out[v * OUT_CH + o] = vals[o] - lse;
}

extern "C" void kernel_launch(void* const* d_in, const int* in_sizes, int n_in,
                              void* d_out, int out_size, void* d_ws, size_t ws_size,
                              hipStream_t stream) {
    const float* x  = (const float*)d_in[0];
    const int*   ei = (const int*)  d_in[1];
    const float* W1 = (const float*)d_in[2];
    const float* b1 = (const float*)d_in[3];
    const float* W2 = (const float*)d_in[4];
    const float* b2 = (const float*)d_in[5];
    float* out = (float*)d_out;

    float* w = (float*)d_ws;
    size_t o = 0;
    // ---- zeroed region (atomic accumulators) ----
    float* sums1 = w + o; o += N_NODES * HID;      // 16384
    float* sums2 = w + o; o += N_NODES * OUT_CH;   // 7168
    float* cdeg  = w + o; o += N_NODES;            // 1024
    float* tes1  = w + o; o += 16;
    float* tes2  = w + o; o += 16;
    int* srcCnt  = (int*)(w + o); o += N_NODES;    // 1024 ints
    const size_t zero_elems = o;
    // ---- non-zeroed region ----
    float* h1    = w + o; o += N_NODES * HID;
    float* h1a   = w + o; o += N_NODES * HID;
    float* h2    = w + o; o += N_NODES * OUT_CH;
    float* xs1   = w + o; o += HID * SP;
    float* ys1   = w + o; o += HID * SP;
    float* zs1   = w + o; o += HID * SP;
    float* xs2   = w + o; o += OUT_CH * SP;
    float* ys2   = w + o; o += OUT_CH * SP;
    float* zs2   = w + o; o += OUT_CH * SP;
    int* rank1   = (int*)(w + o); o += HID * N_NODES;
    int* cur1    = (int*)(w + o); o += HID * N_NODES;
    int* rank2   = (int*)(w + o); o += OUT_CH * N_NODES;
    int* cur2    = (int*)(w + o); o += OUT_CH * N_NODES;

    hipMemsetAsync(d_ws, 0, zero_elems * sizeof(float), stream);

    gemm1_kernel<<<N_NODES, 256, 0, stream>>>(x, W1, b1, h1);
    cnt_kernel<<<(E_TOT + 255) / 256, 256, 0, stream>>>(ei, cdeg, srcCnt);

    // ---- layer 1 TE ----
    sort_kernel<HID><<<HID, 256, 0, stream>>>(h1, srcCnt, rank1, cur1);
    fill_kernel<HID><<<(N_TE * HID + 255) / 256, 256, 0, stream>>>(h1, ei, rank1, cur1,
                                                                   xs1, ys1, zs1);
    te_kernel<HID><<<dim3((N_TE + 15) / 16, HID), 256, 0, stream>>>(xs1, ys1, zs1, tes1);
    agg_kernel<HID><<<(E_TOT * HID + 255) / 256, 256, 0, stream>>>(h1, ei, tes1, 1.0f, sums1);
    fin1_kernel<<<(N_NODES * HID + 255) / 256, 256, 0, stream>>>(sums1, cdeg, h1a);

    // ---- layer 2 ----
    gemm2_kernel<<<(N_NODES * OUT_CH + 255) / 256, 256, 0, stream>>>(h1a, W2, b2, h2);
    sort_kernel<OUT_CH><<<OUT_CH, 256, 0, stream>>>(h2, srcCnt, rank2, cur2);
    fill_kernel<OUT_CH><<<(N_TE * OUT_CH + 255) / 256, 256, 0, stream>>>(h2, ei, rank2, cur2,
                                                                         xs2, ys2, zs2);
    te_kernel<OUT_CH><<<dim3((N_TE + 15) / 16, OUT_CH), 256, 0, stream>>>(xs2, ys2, zs2, tes2);
    agg_kernel<OUT_CH><<<(E_TOT * OUT_CH + 255) / 256, 256, 0, stream>>>(h2, ei, tes2, 0.5f, sums2);
    fin2_kernel<<<(N_NODES + 255) / 256, 256, 0, stream>>>(sums2, cdeg, out);
}

// Round 4
// 289.492 us; speedup vs baseline: 9.8061x; 1.1698x over previous
//
#include <hip/hip_runtime.h>
#include <math.h>
#include <float.h>

#define N_NODES 1024
#define IN_CH   1433
#define HID     16
#define OUT_CH  7
#define N_EDGES 4096
#define E_TOT   5120   // N_EDGES + N_NODES (self loops)
#define N_TE    5119   // embedded series length (valid sorted slots 0..5118)
#define SP      5120   // pitch for per-channel sorted arrays

// psi(x) for integer-valued x >= 1. Recurrence to x>=6 then asymptotic.
// digammaf_dev(0) = -inf, matching jax digamma(0) for the degenerate eps==0 case.
__device__ __forceinline__ float digammaf_dev(float x) {
    float r = 0.0f;
    while (x < 6.0f) { r -= 1.0f / x; x += 1.0f; }
    float inv  = 1.0f / x;
    float inv2 = inv * inv;
    r += logf(x) - 0.5f * inv
       - inv2 * (1.0f/12.0f - inv2 * (1.0f/120.0f - inv2 * (1.0f/252.0f)));
    return r;
}

// h1[r][o] = sum_k x[r][k] * W1[o][k] + b1[o].  One block per row.
__global__ __launch_bounds__(256) void gemm1_kernel(
    const float* __restrict__ x, const float* __restrict__ W1,
    const float* __restrict__ b1, float* __restrict__ h1) {
    __shared__ float xrow[IN_CH];
    const int r = blockIdx.x;
    const float* xr = x + (size_t)r * IN_CH;
    for (int k = threadIdx.x; k < IN_CH; k += 256) xrow[k] = xr[k];
    __syncthreads();
    const int o = threadIdx.x >> 4;
    const int g = threadIdx.x & 15;
    const float* w = W1 + o * IN_CH;
    float s = 0.0f;
    for (int k = g; k < IN_CH; k += 16) s += xrow[k] * w[k];
    #pragma unroll
    for (int m = 8; m >= 1; m >>= 1) s += __shfl_xor(s, m, 16);
    if (g == 0) h1[r * HID + o] = s + b1[o];
}

// degree count per dst (incl. self loop) + src-occurrence count over t<N_TE
__global__ void cnt_kernel(const int* __restrict__ ei, float* __restrict__ cnt,
                           int* __restrict__ srcCnt) {
    int e = blockIdx.x * blockDim.x + threadIdx.x;
    if (e >= E_TOT) return;
    int d = (e < N_EDGES) ? ei[N_EDGES + e] : (e - N_EDGES);
    atomicAdd(&cnt[d], 1.0f);
    if (e < N_TE) {
        int s = (e < N_EDGES) ? ei[e] : (e - N_EDGES);
        atomicAdd(&srcCnt[s], 1);
    }
}

// Per channel c: bitonic-sort the 1024 node values of h[:, c] (key=float as
// sortable uint, payload=node idx), emit rank[c][node] and cursor[c][rank] =
// exclusive prefix of src-multiplicities in rank order (counting-sort offsets).
template <int C>
__global__ __launch_bounds__(256) void sort_kernel(
    const float* __restrict__ h, const int* __restrict__ srcCnt,
    int* __restrict__ rank, int* __restrict__ cursor) {
    __shared__ unsigned long long a[N_NODES];
    const int c = blockIdx.x;
    const int tid = threadIdx.x;
    for (int v = tid; v < N_NODES; v += 256) {
        unsigned u = __float_as_uint(h[v * C + c]);
        u ^= (u & 0x80000000u) ? 0xFFFFFFFFu : 0x80000000u;
        a[v] = ((unsigned long long)u << 32) | (unsigned)v;
    }
    __syncthreads();
    for (int k = 2; k <= N_NODES; k <<= 1) {
        for (int j = k >> 1; j >= 1; j >>= 1) {
            for (int s = tid; s < N_NODES / 2; s += 256) {
                int i  = ((s & ~(j - 1)) << 1) | (s & (j - 1));
                int p2 = i | j;
                unsigned long long A = a[i], B = a[p2];
                bool up = ((i & k) == 0);
                if ((A > B) == up) { a[i] = B; a[p2] = A; }
            }
            __syncthreads();
        }
    }
    // ranks + exclusive prefix sum of src multiplicities in sorted order
    const int r0 = tid * 4;
    int n0 = (int)(a[r0]     & 0xFFFFFFFFu);
    int n1 = (int)(a[r0 + 1] & 0xFFFFFFFFu);
    int n2 = (int)(a[r0 + 2] & 0xFFFFFFFFu);
    int n3 = (int)(a[r0 + 3] & 0xFFFFFFFFu);
    rank[c * N_NODES + n0] = r0;
    rank[c * N_NODES + n1] = r0 + 1;
    rank[c * N_NODES + n2] = r0 + 2;
    rank[c * N_NODES + n3] = r0 + 3;
    int c0 = srcCnt[n0], c1 = srcCnt[n1], c2 = srcCnt[n2], c3 = srcCnt[n3];
    int seg = c0 + c1 + c2 + c3;
    int run = seg;
    const int lane = tid & 63, wid = tid >> 6;
    #pragma unroll
    for (int m = 1; m < 64; m <<= 1) {
        int v = __shfl_up(run, m, 64);
        if (lane >= m) run += v;
    }
    __shared__ int wsum[4];
    if (lane == 63) wsum[wid] = run;
    __syncthreads();
    int base = 0;
    for (int ww = 0; ww < wid; ++ww) base += wsum[ww];
    int excl = base + run - seg;
    cursor[c * N_NODES + r0]     = excl;
    cursor[c * N_NODES + r0 + 1] = excl + c0;
    cursor[c * N_NODES + r0 + 2] = excl + c0 + c1;
    cursor[c * N_NODES + r0 + 3] = excl + c0 + c1 + c2;
}

// Counting-sort fill: scatter each embedded point t into its y-sorted slot.
// Order inside equal-y groups is arbitrary (results order-independent).
template <int C>
__global__ void fill_kernel(const float* __restrict__ h, const int* __restrict__ ei,
                            const int* __restrict__ rank, int* __restrict__ cursor,
                            float* __restrict__ xs, float* __restrict__ ys,
                            float* __restrict__ zs) {
    int idx = blockIdx.x * blockDim.x + threadIdx.x;
    if (idx >= N_TE * C) return;
    int t = idx / C, c = idx % C;
    int s  = (t < N_EDGES)     ? ei[t]     : t - N_EDGES;
    int sn = (t + 1 < N_EDGES) ? ei[t + 1] : t + 1 - N_EDGES;
    int d  = (t < N_EDGES) ? ei[N_EDGES + t] : t - N_EDGES;
    int r = rank[c * N_NODES + s];
    int pos = atomicAdd(&cursor[c * N_NODES + r], 1);
    ys[c * SP + pos] = h[s  * C + c];
    xs[c * SP + pos] = h[d  * C + c];
    zs[c * SP + pos] = h[sn * C + c];
}

// Fused KSG: 32-lane group per point p (sorted position), 512-thread blocks.
// Each round the group covers 128 contiguous elements (one float4 of x/y/z per
// lane) plus a uniform boundary-y read; monotone break conditions.
//   eps phase:   per-lane running best; break via ballot "all lanes have
//                dyB >= best_lane" == "dyB >= group-min" (binding lane is the
//                min-holder) -> identical break point, no per-round reduce.
//                Overshoot exact-safe (d >= |dy| >= boundary dy for skipped j).
//   count phase: exact per-element window predicates; j>p / j<p side masks
//                partition j!=p; breaks are group-uniform (eps,yi,yB uniform).
// Self pair counted iff eps > 0 (cancels ref's -1/+1; preserves
// digamma(0) = -inf in the degenerate duplicate-triple case).
// OOB slots carry y = +/-FLT_MAX sentinels: the |dy| term makes d huge in the
// eps phase and fails the window test in the count phase; fmaxf NaN semantics
// drop garbage x/z terms because the y term dominates.
template <int C>
__global__ __launch_bounds__(512) void te_kernel(
    const float* __restrict__ xs, const float* __restrict__ ys,
    const float* __restrict__ zs, float* __restrict__ tes) {
    constexpr int LOFF = 128;           // left pad (-FLT_MAX)
    constexpr int LSZ  = LOFF + SP;     // 5248 floats per array
    __shared__ __align__(16) float Xs[LSZ];
    __shared__ __align__(16) float Ys[LSZ];
    __shared__ __align__(16) float Zs[LSZ];
    const int c = blockIdx.y;
    const int tid = threadIdx.x;
    {
        const float4* gx4 = (const float4*)(xs + (size_t)c * SP);
        const float4* gy4 = (const float4*)(ys + (size_t)c * SP);
        const float4* gz4 = (const float4*)(zs + (size_t)c * SP);
        float4* lx4 = (float4*)(Xs + LOFF);
        float4* ly4 = (float4*)(Ys + LOFF);
        float4* lz4 = (float4*)(Zs + LOFF);
        for (int t = tid; t < SP / 4; t += 512) {
            lx4[t] = gx4[t]; ly4[t] = gy4[t]; lz4[t] = gz4[t];
        }
        if (tid < LOFF) {  // left pad
            Xs[tid] = -FLT_MAX; Ys[tid] = -FLT_MAX; Zs[tid] = -FLT_MAX;
        }
    }
    __syncthreads();
    if (tid == 0) {  // right sentinel at sorted slot N_TE (was staged garbage)
        Xs[LOFF + N_TE] = FLT_MAX; Ys[LOFF + N_TE] = FLT_MAX; Zs[LOFF + N_TE] = FLT_MAX;
    }
    __syncthreads();

    const int g = tid >> 5, l = tid & 31;
    const unsigned hsh = (g & 1) * 32;       // this group's half of the wave ballot
    const int p = blockIdx.x * 16 + g;
    float local = 0.0f;
    if (p < N_TE) {
        const float xi = Xs[LOFF + p], yi = Ys[LOFF + p], zi = Zs[LOFF + p];
        const int base = p & ~127;
        const int lo = 4 * l;
        float best = FLT_MAX;
        // ---- eps: right/up (includes base block, j==p masked) ----
        for (int b = base; ; b += 128) {
            const int j0 = b + lo;
            const float4 xv = *(const float4*)(Xs + LOFF + j0);
            const float4 yv = *(const float4*)(Ys + LOFF + j0);
            const float4 zv = *(const float4*)(Zs + LOFF + j0);
            const float yB = Ys[LOFF + b + 127];      // uniform broadcast
            float d0 = fmaxf(fmaxf(fabsf(xv.x - xi), fabsf(yv.x - yi)), fabsf(zv.x - zi));
            float d1 = fmaxf(fmaxf(fabsf(xv.y - xi), fabsf(yv.y - yi)), fabsf(zv.y - zi));
            float d2 = fmaxf(fmaxf(fabsf(xv.z - xi), fabsf(yv.z - yi)), fabsf(zv.z - zi));
            float d3 = fmaxf(fmaxf(fabsf(xv.w - xi), fabsf(yv.w - yi)), fabsf(zv.w - zi));
            d0 = (j0     == p) ? FLT_MAX : d0;
            d1 = (j0 + 1 == p) ? FLT_MAX : d1;
            d2 = (j0 + 2 == p) ? FLT_MAX : d2;
            d3 = (j0 + 3 == p) ? FLT_MAX : d3;
            best = fminf(best, fminf(fminf(d0, d1), fminf(d2, d3)));
            unsigned long long vote = __ballot(yB - yi >= best);
            if ((unsigned)(vote >> hsh) == 0xFFFFFFFFu) break;
        }
        // ---- eps: left/down (strictly below base; no j==p possible) ----
        for (int b = base - 128; ; b -= 128) {
            const int j0 = b + lo;
            const float4 xv = *(const float4*)(Xs + LOFF + j0);
            const float4 yv = *(const float4*)(Ys + LOFF + j0);
            const float4 zv = *(const float4*)(Zs + LOFF + j0);
            const float yB = Ys[LOFF + b];            // uniform broadcast
            float d0 = fmaxf(fmaxf(fabsf(xv.x - xi), fabsf(yv.x - yi)), fabsf(zv.x - zi));
            float d1 = fmaxf(fmaxf(fabsf(xv.y - xi), fabsf(yv.y - yi)), fabsf(zv.y - zi));
            float d2 = fmaxf(fmaxf(fabsf(xv.z - xi), fabsf(yv.z - yi)), fabsf(zv.z - zi));
            float d3 = fmaxf(fmaxf(fabsf(xv.w - xi), fabsf(yv.w - yi)), fabsf(zv.w - zi));
            best = fminf(best, fminf(fminf(d0, d1), fminf(d2, d3)));
            unsigned long long vote = __ballot(yi - yB >= best);
            if ((unsigned)(vote >> hsh) == 0xFFFFFFFFu) break;
        }
        #pragma unroll
        for (int m = 1; m < 32; m <<= 1) best = fminf(best, __shfl_xor(best, m, 32));
        const float eps = best;
        int inc = (l == 0 && 0.0f < eps) ? 1 : 0;
        int ny = inc, nxy = inc, nyz = inc;
        // ---- count: right (j > p) ----
        for (int b = base; ; b += 128) {
            const int j0 = b + lo;
            const float4 xv = *(const float4*)(Xs + LOFF + j0);
            const float4 yv = *(const float4*)(Ys + LOFF + j0);
            const float4 zv = *(const float4*)(Zs + LOFF + j0);
            const float yB = Ys[LOFF + b + 127];
            int w0 = (int)(j0     > p) & (int)(fabsf(yv.x - yi) < eps);
            int w1 = (int)(j0 + 1 > p) & (int)(fabsf(yv.y - yi) < eps);
            int w2 = (int)(j0 + 2 > p) & (int)(fabsf(yv.z - yi) < eps);
            int w3 = (int)(j0 + 3 > p) & (int)(fabsf(yv.w - yi) < eps);
            ny  += w0 + w1 + w2 + w3;
            nxy += (w0 & (int)(fabsf(xv.x - xi) < eps)) + (w1 & (int)(fabsf(xv.y - xi) < eps))
                 + (w2 & (int)(fabsf(xv.z - xi) < eps)) + (w3 & (int)(fabsf(xv.w - xi) < eps));
            nyz += (w0 & (int)(fabsf(zv.x - zi) < eps)) + (w1 & (int)(fabsf(zv.y - zi) < eps))
                 + (w2 & (int)(fabsf(zv.z - zi) < eps)) + (w3 & (int)(fabsf(zv.w - zi) < eps));
            if (yB - yi >= eps) break;    // window contiguous in sorted y
        }
        // ---- count: left (j < p; includes base block) ----
        for (int b = base; ; b -= 128) {
            const int j0 = b + lo;
            const float4 xv = *(const float4*)(Xs + LOFF + j0);
            const float4 yv = *(const float4*)(Ys + LOFF + j0);
            const float4 zv = *(const float4*)(Zs + LOFF + j0);
            const float yB = Ys[LOFF + b];
            int w0 = (int)(j0     < p) & (int)(fabsf(yv.x - yi) < eps);
            int w1 = (int)(j0 + 1 < p) & (int)(fabsf(yv.y - yi) < eps);
            int w2 = (int)(j0 + 2 < p) & (int)(fabsf(yv.z - yi) < eps);
            int w3 = (int)(j0 + 3 < p) & (int)(fabsf(yv.w - yi) < eps);
            ny  += w0 + w1 + w2 + w3;
            nxy += (w0 & (int)(fabsf(xv.x - xi) < eps)) + (w1 & (int)(fabsf(xv.y - xi) < eps))
                 + (w2 & (int)(fabsf(xv.z - xi) < eps)) + (w3 & (int)(fabsf(xv.w - xi) < eps));
            nyz += (w0 & (int)(fabsf(zv.x - zi) < eps)) + (w1 & (int)(fabsf(zv.y - zi) < eps))
                 + (w2 & (int)(fabsf(zv.z - zi) < eps)) + (w3 & (int)(fabsf(zv.w - zi) < eps));
            if (yi - yB >= eps) break;
        }
        // ---- group reduce: ny,nxy packed (each <= 5120 < 8192), nyz separate
        int pack = (ny << 13) | nxy;
        #pragma unroll
        for (int m = 1; m < 32; m <<= 1) {
            pack += __shfl_xor(pack, m, 32);
            nyz  += __shfl_xor(nyz, m, 32);
        }
        if (l == 0) {
            ny  = pack >> 13;
            nxy = pack & 8191;
            local = digammaf_dev((float)ny) - digammaf_dev((float)nxy)
                  - digammaf_dev((float)nyz);
        }
    }
    #pragma unroll
    for (int m = 32; m >= 1; m >>= 1) local += __shfl_xor(local, m, 64);
    __shared__ float wsum[8];
    if ((threadIdx.x & 63) == 0) wsum[threadIdx.x >> 6] = local;
    __syncthreads();
    if (threadIdx.x == 0)
        atomicAdd(&tes[c], wsum[0] + wsum[1] + wsum[2] + wsum[3]
                         + wsum[4] + wsum[5] + wsum[6] + wsum[7]);
}

// msg = sigmoid(te_c * h[src][c]); segment-sum into sums[dst][c]
template <int C>
__global__ void agg_kernel(const float* __restrict__ h, const int* __restrict__ ei,
                           const float* __restrict__ tes_accum, float half_scale,
                           float* __restrict__ sums) {
    int idx = blockIdx.x * blockDim.x + threadIdx.x;
    if (idx >= E_TOT * C) return;
    int e = idx / C, c = idx % C;
    int s = (e < N_EDGES) ? ei[e] : (e - N_EDGES);
    int d = (e < N_EDGES) ? ei[N_EDGES + e] : (e - N_EDGES);
    float te = (-0.57721566490153286f + tes_accum[c] * (1.0f / (float)N_TE)) * half_scale;
    float xj = h[s * C + c];
    float m = 1.0f / (1.0f + expf(-te * xj));
    atomicAdd(&sums[d * C + c], m);
}

__global__ void fin1_kernel(const float* __restrict__ sums, const float* __restrict__ cnt,
                            float* __restrict__ h1a) {
    int idx = blockIdx.x * blockDim.x + threadIdx.x;
    if (idx >= N_NODES * HID) return;
    int v = idx / HID;
    float val = sums[idx] / fmaxf(cnt[v], 1.0f);
    h1a[idx] = fmaxf(val, 0.0f);
}

__global__ void gemm2_kernel(const float* __restrict__ h1a, const float* __restrict__ W2,
                             const float* __restrict__ b2, float* __restrict__ h2) {
    int idx = blockIdx.x * blockDim.x + threadIdx.x;
    if (idx >= N_NODES * OUT_CH) return;
    int v = idx / OUT_CH, o = idx % OUT_CH;
    float s = b2[o];
    #pragma unroll
    for (int k = 0; k < HID; ++k) s += h1a[v * HID + k] * W2[o * HID + k];
    h2[idx] = s;
}

__global__ void fin2_kernel(const float* __restrict__ sums2, const float* __restrict__ cnt,
                            float* __restrict__ out) {
    int v = blockIdx.x * blockDim.x + threadIdx.x;
    if (v >= N_NODES) return;
    float c = fmaxf(cnt[v], 1.0f);
    float vals[OUT_CH];
    float mx = -INFINITY;
    #pragma unroll
    for (int o = 0; o < OUT_CH; ++o) {
        vals[o] = sums2[v * OUT_CH + o] / c;
        mx = fmaxf(mx, vals[o]);
    }
    float se = 0.0f;
    #pragma unroll
    for (int o = 0; o < OUT_CH; ++o) se += expf(vals[o] - mx);
    float lse = mx + logf(se);
    #pragma unroll
    for (int o = 0; o < OUT_CH; ++o) out[v * OUT_CH + o] = vals[o] - lse;
}

extern "C" void kernel_launch(void* const* d_in, const int* in_sizes, int n_in,
                              void* d_out, int out_size, void* d_ws, size_t ws_size,
                              hipStream_t stream) {
    const float* x  = (const float*)d_in[0];
    const int*   ei = (const int*)  d_in[1];
    const float* W1 = (const float*)d_in[2];
    const float* b1 = (const float*)d_in[3];
    const float* W2 = (const float*)d_in[4];
    const float* b2 = (const float*)d_in[5];
    float* out = (float*)d_out;

    float* w = (float*)d_ws;
    size_t o = 0;
    // ---- zeroed region (atomic accumulators) ----
    float* sums1 = w + o; o += N_NODES * HID;      // 16384
    float* sums2 = w + o; o += N_NODES * OUT_CH;   // 7168
    float* cdeg  = w + o; o += N_NODES;            // 1024
    float* tes1  = w + o; o += 16;
    float* tes2  = w + o; o += 16;
    int* srcCnt  = (int*)(w + o); o += N_NODES;    // 1024 ints
    const size_t zero_elems = o;
    // ---- non-zeroed region ----
    float* h1    = w + o; o += N_NODES * HID;
    float* h1a   = w + o; o += N_NODES * HID;
    float* h2    = w + o; o += N_NODES * OUT_CH;
    float* xs1   = w + o; o += HID * SP;
    float* ys1   = w + o; o += HID * SP;
    float* zs1   = w + o; o += HID * SP;
    float* xs2   = w + o; o += OUT_CH * SP;
    float* ys2   = w + o; o += OUT_CH * SP;
    float* zs2   = w + o; o += OUT_CH * SP;
    int* rank1   = (int*)(w + o); o += HID * N_NODES;
    int* cur1    = (int*)(w + o); o += HID * N_NODES;
    int* rank2   = (int*)(w + o); o += OUT_CH * N_NODES;
    int* cur2    = (int*)(w + o); o += OUT_CH * N_NODES;

    hipMemsetAsync(d_ws, 0, zero_elems * sizeof(float), stream);

    gemm1_kernel<<<N_NODES, 256, 0, stream>>>(x, W1, b1, h1);
    cnt_kernel<<<(E_TOT + 255) / 256, 256, 0, stream>>>(ei, cdeg, srcCnt);

    // ---- layer 1 TE ----
    sort_kernel<HID><<<HID, 256, 0, stream>>>(h1, srcCnt, rank1, cur1);
    fill_kernel<HID><<<(N_TE * HID + 255) / 256, 256, 0, stream>>>(h1, ei, rank1, cur1,
                                                                   xs1, ys1, zs1);
    te_kernel<HID><<<dim3((N_TE + 15) / 16, HID), 512, 0, stream>>>(xs1, ys1, zs1, tes1);
    agg_kernel<HID><<<(E_TOT * HID + 255) / 256, 256, 0, stream>>>(h1, ei, tes1, 1.0f, sums1);
    fin1_kernel<<<(N_NODES * HID + 255) / 256, 256, 0, stream>>>(sums1, cdeg, h1a);

    // ---- layer 2 ----
    gemm2_kernel<<<(N_NODES * OUT_CH + 255) / 256, 256, 0, stream>>>(h1a, W2, b2, h2);
    sort_kernel<OUT_CH><<<OUT_CH, 256, 0, stream>>>(h2, srcCnt, rank2, cur2);
    fill_kernel<OUT_CH><<<(N_TE * OUT_CH + 255) / 256, 256, 0, stream>>>(h2, ei, rank2, cur2,
                                                                         xs2, ys2, zs2);
    te_kernel<OUT_CH><<<dim3((N_TE + 15) / 16, OUT_CH), 512, 0, stream>>>(xs2, ys2, zs2, tes2);
    agg_kernel<OUT_CH><<<(E_TOT * OUT_CH + 255) / 256, 256, 0, stream>>>(h2, ei, tes2, 0.5f, sums2);
    fin2_kernel<<<(N_NODES + 255) / 256, 256, 0, stream>>>(sums2, cdeg, out);
}

// Round 5
// 263.873 us; speedup vs baseline: 10.7581x; 1.0971x over previous
//
#include <hip/hip_runtime.h>
#include <math.h>
#include <float.h>

#define N_NODES 1024
#define IN_CH   1433
#define HID     16
#define OUT_CH  7
#define N_EDGES 4096
#define E_TOT   5120   // N_EDGES + N_NODES (self loops)
#define N_TE    5119   // embedded series length (valid sorted slots 0..5118)
#define SP      5120   // pitch for per-channel sorted arrays

// psi(x) for integer-valued x >= 1. Recurrence to x>=6 then asymptotic.
// digammaf_dev(0) = -inf, matching jax digamma(0) for the degenerate eps==0 case.
__device__ __forceinline__ float digammaf_dev(float x) {
    float r = 0.0f;
    while (x < 6.0f) { r -= 1.0f / x; x += 1.0f; }
    float inv  = 1.0f / x;
    float inv2 = inv * inv;
    r += logf(x) - 0.5f * inv
       - inv2 * (1.0f/12.0f - inv2 * (1.0f/120.0f - inv2 * (1.0f/252.0f)));
    return r;
}

// h1[r][o] = sum_k x[r][k] * W1[o][k] + b1[o].  One block per row.
__global__ __launch_bounds__(256) void gemm1_kernel(
    const float* __restrict__ x, const float* __restrict__ W1,
    const float* __restrict__ b1, float* __restrict__ h1) {
    __shared__ float xrow[IN_CH];
    const int r = blockIdx.x;
    const float* xr = x + (size_t)r * IN_CH;
    for (int k = threadIdx.x; k < IN_CH; k += 256) xrow[k] = xr[k];
    __syncthreads();
    const int o = threadIdx.x >> 4;
    const int g = threadIdx.x & 15;
    const float* w = W1 + o * IN_CH;
    float s = 0.0f;
    for (int k = g; k < IN_CH; k += 16) s += xrow[k] * w[k];
    #pragma unroll
    for (int m = 8; m >= 1; m >>= 1) s += __shfl_xor(s, m, 16);
    if (g == 0) h1[r * HID + o] = s + b1[o];
}

// degree count per dst (incl. self loop) + src-occurrence count over t<N_TE
__global__ void cnt_kernel(const int* __restrict__ ei, float* __restrict__ cnt,
                           int* __restrict__ srcCnt) {
    int e = blockIdx.x * blockDim.x + threadIdx.x;
    if (e >= E_TOT) return;
    int d = (e < N_EDGES) ? ei[N_EDGES + e] : (e - N_EDGES);
    atomicAdd(&cnt[d], 1.0f);
    if (e < N_TE) {
        int s = (e < N_EDGES) ? ei[e] : (e - N_EDGES);
        atomicAdd(&srcCnt[s], 1);
    }
}

// Per channel c: bitonic-sort the 1024 node values of h[:, c] (key=float as
// sortable uint, payload=node idx), emit rank[c][node] and cursor[c][rank] =
// exclusive prefix of src-multiplicities in rank order (counting-sort offsets).
template <int C>
__global__ __launch_bounds__(256) void sort_kernel(
    const float* __restrict__ h, const int* __restrict__ srcCnt,
    int* __restrict__ rank, int* __restrict__ cursor) {
    __shared__ unsigned long long a[N_NODES];
    const int c = blockIdx.x;
    const int tid = threadIdx.x;
    for (int v = tid; v < N_NODES; v += 256) {
        unsigned u = __float_as_uint(h[v * C + c]);
        u ^= (u & 0x80000000u) ? 0xFFFFFFFFu : 0x80000000u;
        a[v] = ((unsigned long long)u << 32) | (unsigned)v;
    }
    __syncthreads();
    for (int k = 2; k <= N_NODES; k <<= 1) {
        for (int j = k >> 1; j >= 1; j >>= 1) {
            for (int s = tid; s < N_NODES / 2; s += 256) {
                int i  = ((s & ~(j - 1)) << 1) | (s & (j - 1));
                int p2 = i | j;
                unsigned long long A = a[i], B = a[p2];
                bool up = ((i & k) == 0);
                if ((A > B) == up) { a[i] = B; a[p2] = A; }
            }
            __syncthreads();
        }
    }
    // ranks + exclusive prefix sum of src multiplicities in sorted order
    const int r0 = tid * 4;
    int n0 = (int)(a[r0]     & 0xFFFFFFFFu);
    int n1 = (int)(a[r0 + 1] & 0xFFFFFFFFu);
    int n2 = (int)(a[r0 + 2] & 0xFFFFFFFFu);
    int n3 = (int)(a[r0 + 3] & 0xFFFFFFFFu);
    rank[c * N_NODES + n0] = r0;
    rank[c * N_NODES + n1] = r0 + 1;
    rank[c * N_NODES + n2] = r0 + 2;
    rank[c * N_NODES + n3] = r0 + 3;
    int c0 = srcCnt[n0], c1 = srcCnt[n1], c2 = srcCnt[n2], c3 = srcCnt[n3];
    int seg = c0 + c1 + c2 + c3;
    int run = seg;
    const int lane = tid & 63, wid = tid >> 6;
    #pragma unroll
    for (int m = 1; m < 64; m <<= 1) {
        int v = __shfl_up(run, m, 64);
        if (lane >= m) run += v;
    }
    __shared__ int wsum[4];
    if (lane == 63) wsum[wid] = run;
    __syncthreads();
    int base = 0;
    for (int ww = 0; ww < wid; ++ww) base += wsum[ww];
    int excl = base + run - seg;
    cursor[c * N_NODES + r0]     = excl;
    cursor[c * N_NODES + r0 + 1] = excl + c0;
    cursor[c * N_NODES + r0 + 2] = excl + c0 + c1;
    cursor[c * N_NODES + r0 + 3] = excl + c0 + c1 + c2;
}

// Counting-sort fill: scatter each embedded point t into its y-sorted slot.
// Order inside equal-y groups is arbitrary (results order-independent).
template <int C>
__global__ void fill_kernel(const float* __restrict__ h, const int* __restrict__ ei,
                            const int* __restrict__ rank, int* __restrict__ cursor,
                            float* __restrict__ xs, float* __restrict__ ys,
                            float* __restrict__ zs) {
    int idx = blockIdx.x * blockDim.x + threadIdx.x;
    if (idx >= N_TE * C) return;
    int t = idx / C, c = idx % C;
    int s  = (t < N_EDGES)     ? ei[t]     : t - N_EDGES;
    int sn = (t + 1 < N_EDGES) ? ei[t + 1] : t + 1 - N_EDGES;
    int d  = (t < N_EDGES) ? ei[N_EDGES + t] : t - N_EDGES;
    int r = rank[c * N_NODES + s];
    int pos = atomicAdd(&cursor[c * N_NODES + r], 1);
    ys[c * SP + pos] = h[s  * C + c];
    xs[c * SP + pos] = h[d  * C + c];
    zs[c * SP + pos] = h[sn * C + c];
}

// Fused KSG: ONE 64-lane wave per point p (sorted position), 1024-thread
// blocks (16 points/block share one LDS staging). Rounds of 256 elements
// (one float4 of x/y/z per lane), software-prefetched (next round's loads +
// boundary issued before computing the current round).
//   eps phase:   per-lane running best; break when ANY lane has dyB >= best_l
//                — exactly dyB >= wave-min(best) (the arg-min lane's vote),
//                the optimal exact stop. Overshoot-safe (d >= |dy|).
//   count phase: window predicates via ballot+popcount — counts accumulate
//                wave-uniform in SGPRs on the scalar pipe. Right scan owns
//                the whole base round, left scan starts below it: no side
//                masks, and the self pair (0<eps on all three axes) IS the
//                +1-inside-psi convention. eps<=0 short-circuits to counts 0
//                -> digamma(0) = -inf, matching the reference degenerate case.
// Sentinels: left pad -FLT_MAX, right pad / slot N_TE +FLT_MAX — fail every
// predicate and force boundary breaks; prefetch stays inside the padding.
template <int C>
__global__ __launch_bounds__(1024, 4) void te_kernel(
    const float* __restrict__ xs, const float* __restrict__ ys,
    const float* __restrict__ zs, float* __restrict__ tes) {
    constexpr int LOFF = 512;            // left pad
    constexpr int LSZ  = 5888;           // LOFF + SP + 256 (covers prefetch)
    __shared__ __align__(16) float Xs[LSZ];
    __shared__ __align__(16) float Ys[LSZ];
    __shared__ __align__(16) float Zs[LSZ];
    const int c = blockIdx.y;
    const int tid = threadIdx.x;
    {
        const float4* gx4 = (const float4*)(xs + (size_t)c * SP);
        const float4* gy4 = (const float4*)(ys + (size_t)c * SP);
        const float4* gz4 = (const float4*)(zs + (size_t)c * SP);
        float4* lx4 = (float4*)(Xs + LOFF);
        float4* ly4 = (float4*)(Ys + LOFF);
        float4* lz4 = (float4*)(Zs + LOFF);
        for (int t = tid; t < SP / 4; t += 1024) {
            lx4[t] = gx4[t]; ly4[t] = gy4[t]; lz4[t] = gz4[t];
        }
        for (int t = tid; t < LOFF; t += 1024) {
            Xs[t] = -FLT_MAX; Ys[t] = -FLT_MAX; Zs[t] = -FLT_MAX;
        }
        for (int t = LOFF + SP + tid; t < LSZ; t += 1024) {
            Xs[t] = FLT_MAX; Ys[t] = FLT_MAX; Zs[t] = FLT_MAX;
        }
    }
    __syncthreads();
    if (tid == 0) {  // slot N_TE holds fill garbage; make it a sentinel
        Xs[LOFF + N_TE] = FLT_MAX; Ys[LOFF + N_TE] = FLT_MAX; Zs[LOFF + N_TE] = FLT_MAX;
    }
    __syncthreads();

    const int wv = tid >> 6, l = tid & 63;
    const int p = blockIdx.x * 16 + wv;
    float local = 0.0f;
    if (p < N_TE) {
        const float xi = Xs[LOFF + p], yi = Ys[LOFF + p], zi = Zs[LOFF + p];
        const int base = p & ~255;
        const int lo4 = l * 4;

#define LD4(arr, idx) (*(const float4*)((arr) + LOFF + (idx)))
#define TE_D(xc, yc, zc) \
    fmaxf(fmaxf(fabsf((xc) - xi), fabsf((yc) - yi)), fabsf((zc) - zi))

        float best = FLT_MAX;
        // ---- eps: right/up (includes base round; j==p masked) ----
        {
            int b = base;
            float4 x0 = LD4(Xs, b + lo4), y0 = LD4(Ys, b + lo4), z0 = LD4(Zs, b + lo4);
            float yB0 = Ys[LOFF + b + 255];
            while (true) {
                float4 x1 = LD4(Xs, b + 256 + lo4);
                float4 y1 = LD4(Ys, b + 256 + lo4);
                float4 z1 = LD4(Zs, b + 256 + lo4);
                float yB1 = Ys[LOFF + b + 511];
                const int j0 = b + lo4;
                float d0 = TE_D(x0.x, y0.x, z0.x);
                float d1 = TE_D(x0.y, y0.y, z0.y);
                float d2 = TE_D(x0.z, y0.z, z0.z);
                float d3 = TE_D(x0.w, y0.w, z0.w);
                d0 = (j0     == p) ? FLT_MAX : d0;
                d1 = (j0 + 1 == p) ? FLT_MAX : d1;
                d2 = (j0 + 2 == p) ? FLT_MAX : d2;
                d3 = (j0 + 3 == p) ? FLT_MAX : d3;
                best = fminf(fminf(best, d0), fminf(fminf(d1, d2), d3));
                if (__ballot(yB0 - yi >= best) != 0ull) break;   // wave-min stop
                x0 = x1; y0 = y1; z0 = z1; yB0 = yB1; b += 256;
            }
        }
        // ---- eps: left/down (strictly below base; no j==p) ----
        {
            int b = base - 256;
            float4 x0 = LD4(Xs, b + lo4), y0 = LD4(Ys, b + lo4), z0 = LD4(Zs, b + lo4);
            float yB0 = Ys[LOFF + b];
            while (true) {
                float4 x1 = LD4(Xs, b - 256 + lo4);
                float4 y1 = LD4(Ys, b - 256 + lo4);
                float4 z1 = LD4(Zs, b - 256 + lo4);
                float yB1 = Ys[LOFF + b - 256];
                float d0 = TE_D(x0.x, y0.x, z0.x);
                float d1 = TE_D(x0.y, y0.y, z0.y);
                float d2 = TE_D(x0.z, y0.z, z0.z);
                float d3 = TE_D(x0.w, y0.w, z0.w);
                best = fminf(fminf(best, d0), fminf(fminf(d1, d2), d3));
                if (__ballot(yi - yB0 >= best) != 0ull) break;   // wave-min stop
                x0 = x1; y0 = y1; z0 = z1; yB0 = yB1; b -= 256;
            }
        }
        #pragma unroll
        for (int m = 1; m < 64; m <<= 1) best = fminf(best, __shfl_xor(best, m, 64));
        const float eps = best;

        int ny = 0, nxy = 0, nyz = 0;
        if (eps > 0.0f) {
#define TE_CSLOT(xc, yc, zc)                                                 \
    {                                                                        \
        unsigned long long my_ = __ballot(fabsf((yc) - yi) < eps);           \
        unsigned long long mx_ = __ballot(fabsf((xc) - xi) < eps);           \
        unsigned long long mz_ = __ballot(fabsf((zc) - zi) < eps);           \
        ny  += __popcll(my_);                                                \
        nxy += __popcll(my_ & mx_);                                          \
        nyz += __popcll(my_ & mz_);                                          \
    }
            // ---- count: right (whole base round + up; self included) ----
            {
                int b = base;
                float4 x0 = LD4(Xs, b + lo4), y0 = LD4(Ys, b + lo4), z0 = LD4(Zs, b + lo4);
                float yB0 = Ys[LOFF + b + 255];
                while (true) {
                    float4 x1 = LD4(Xs, b + 256 + lo4);
                    float4 y1 = LD4(Ys, b + 256 + lo4);
                    float4 z1 = LD4(Zs, b + 256 + lo4);
                    float yB1 = Ys[LOFF + b + 511];
                    TE_CSLOT(x0.x, y0.x, z0.x)
                    TE_CSLOT(x0.y, y0.y, z0.y)
                    TE_CSLOT(x0.z, y0.z, z0.z)
                    TE_CSLOT(x0.w, y0.w, z0.w)
                    if (yB0 - yi >= eps) break;      // uniform: window covered
                    x0 = x1; y0 = y1; z0 = z1; yB0 = yB1; b += 256;
                }
            }
            // ---- count: left (strictly below base) ----
            {
                int b = base - 256;
                float4 x0 = LD4(Xs, b + lo4), y0 = LD4(Ys, b + lo4), z0 = LD4(Zs, b + lo4);
                float yB0 = Ys[LOFF + b];
                while (true) {
                    float4 x1 = LD4(Xs, b - 256 + lo4);
                    float4 y1 = LD4(Ys, b - 256 + lo4);
                    float4 z1 = LD4(Zs, b - 256 + lo4);
                    float yB1 = Ys[LOFF + b - 256];
                    TE_CSLOT(x0.x, y0.x, z0.x)
                    TE_CSLOT(x0.y, y0.y, z0.y)
                    TE_CSLOT(x0.z, y0.z, z0.z)
                    TE_CSLOT(x0.w, y0.w, z0.w)
                    if (yi - yB0 >= eps) break;
                    x0 = x1; y0 = y1; z0 = z1; yB0 = yB1; b -= 256;
                }
            }
#undef TE_CSLOT
        }
        if (l == 0)
            local = digammaf_dev((float)ny) - digammaf_dev((float)nxy)
                  - digammaf_dev((float)nyz);
#undef LD4
#undef TE_D
    }
    __shared__ float wred[16];
    if (l == 0) wred[wv] = local;
    __syncthreads();
    if (tid == 0) {
        float s = 0.0f;
        #pragma unroll
        for (int i = 0; i < 16; ++i) s += wred[i];
        atomicAdd(&tes[c], s);
    }
}

// msg = sigmoid(te_c * h[src][c]); segment-sum into sums[dst][c]
template <int C>
__global__ void agg_kernel(const float* __restrict__ h, const int* __restrict__ ei,
                           const float* __restrict__ tes_accum, float half_scale,
                           float* __restrict__ sums) {
    int idx = blockIdx.x * blockDim.x + threadIdx.x;
    if (idx >= E_TOT * C) return;
    int e = idx / C, c = idx % C;
    int s = (e < N_EDGES) ? ei[e] : (e - N_EDGES);
    int d = (e < N_EDGES) ? ei[N_EDGES + e] : (e - N_EDGES);
    float te = (-0.57721566490153286f + tes_accum[c] * (1.0f / (float)N_TE)) * half_scale;
    float xj = h[s * C + c];
    float m = 1.0f / (1.0f + expf(-te * xj));
    atomicAdd(&sums[d * C + c], m);
}

__global__ void fin1_kernel(const float* __restrict__ sums, const float* __restrict__ cnt,
                            float* __restrict__ h1a) {
    int idx = blockIdx.x * blockDim.x + threadIdx.x;
    if (idx >= N_NODES * HID) return;
    int v = idx / HID;
    float val = sums[idx] / fmaxf(cnt[v], 1.0f);
    h1a[idx] = fmaxf(val, 0.0f);
}

__global__ void gemm2_kernel(const float* __restrict__ h1a, const float* __restrict__ W2,
                             const float* __restrict__ b2, float* __restrict__ h2) {
    int idx = blockIdx.x * blockDim.x + threadIdx.x;
    if (idx >= N_NODES * OUT_CH) return;
    int v = idx / OUT_CH, o = idx % OUT_CH;
    float s = b2[o];
    #pragma unroll
    for (int k = 0; k < HID; ++k) s += h1a[v * HID + k] * W2[o * HID + k];
    h2[idx] = s;
}

__global__ void fin2_kernel(const float* __restrict__ sums2, const float* __restrict__ cnt,
                            float* __restrict__ out) {
    int v = blockIdx.x * blockDim.x + threadIdx.x;
    if (v >= N_NODES) return;
    float c = fmaxf(cnt[v], 1.0f);
    float vals[OUT_CH];
    float mx = -INFINITY;
    #pragma unroll
    for (int o = 0; o < OUT_CH; ++o) {
        vals[o] = sums2[v * OUT_CH + o] / c;
        mx = fmaxf(mx, vals[o]);
    }
    float se = 0.0f;
    #pragma unroll
    for (int o = 0; o < OUT_CH; ++o) se += expf(vals[o] - mx);
    float lse = mx + logf(se);
    #pragma unroll
    for (int o = 0; o < OUT_CH; ++o) out[v * OUT_CH + o] = vals[o] - lse;
}

extern "C" void kernel_launch(void* const* d_in, const int* in_sizes, int n_in,
                              void* d_out, int out_size, void* d_ws, size_t ws_size,
                              hipStream_t stream) {
    const float* x  = (const float*)d_in[0];
    const int*   ei = (const int*)  d_in[1];
    const float* W1 = (const float*)d_in[2];
    const float* b1 = (const float*)d_in[3];
    const float* W2 = (const float*)d_in[4];
    const float* b2 = (const float*)d_in[5];
    float* out = (float*)d_out;

    float* w = (float*)d_ws;
    size_t o = 0;
    // ---- zeroed region (atomic accumulators) ----
    float* sums1 = w + o; o += N_NODES * HID;      // 16384
    float* sums2 = w + o; o += N_NODES * OUT_CH;   // 7168
    float* cdeg  = w + o; o += N_NODES;            // 1024
    float* tes1  = w + o; o += 16;
    float* tes2  = w + o; o += 16;
    int* srcCnt  = (int*)(w + o); o += N_NODES;    // 1024 ints
    const size_t zero_elems = o;
    // ---- non-zeroed region ----
    float* h1    = w + o; o += N_NODES * HID;
    float* h1a   = w + o; o += N_NODES * HID;
    float* h2    = w + o; o += N_NODES * OUT_CH;
    float* xs1   = w + o; o += HID * SP;
    float* ys1   = w + o; o += HID * SP;
    float* zs1   = w + o; o += HID * SP;
    float* xs2   = w + o; o += OUT_CH * SP;
    float* ys2   = w + o; o += OUT_CH * SP;
    float* zs2   = w + o; o += OUT_CH * SP;
    int* rank1   = (int*)(w + o); o += HID * N_NODES;
    int* cur1    = (int*)(w + o); o += HID * N_NODES;
    int* rank2   = (int*)(w + o); o += OUT_CH * N_NODES;
    int* cur2    = (int*)(w + o); o += OUT_CH * N_NODES;

    hipMemsetAsync(d_ws, 0, zero_elems * sizeof(float), stream);

    gemm1_kernel<<<N_NODES, 256, 0, stream>>>(x, W1, b1, h1);
    cnt_kernel<<<(E_TOT + 255) / 256, 256, 0, stream>>>(ei, cdeg, srcCnt);

    // ---- layer 1 TE ----
    sort_kernel<HID><<<HID, 256, 0, stream>>>(h1, srcCnt, rank1, cur1);
    fill_kernel<HID><<<(N_TE * HID + 255) / 256, 256, 0, stream>>>(h1, ei, rank1, cur1,
                                                                   xs1, ys1, zs1);
    te_kernel<HID><<<dim3((N_TE + 15) / 16, HID), 1024, 0, stream>>>(xs1, ys1, zs1, tes1);
    agg_kernel<HID><<<(E_TOT * HID + 255) / 256, 256, 0, stream>>>(h1, ei, tes1, 1.0f, sums1);
    fin1_kernel<<<(N_NODES * HID + 255) / 256, 256, 0, stream>>>(sums1, cdeg, h1a);

    // ---- layer 2 ----
    gemm2_kernel<<<(N_NODES * OUT_CH + 255) / 256, 256, 0, stream>>>(h1a, W2, b2, h2);
    sort_kernel<OUT_CH><<<OUT_CH, 256, 0, stream>>>(h2, srcCnt, rank2, cur2);
    fill_kernel<OUT_CH><<<(N_TE * OUT_CH + 255) / 256, 256, 0, stream>>>(h2, ei, rank2, cur2,
                                                                         xs2, ys2, zs2);
    te_kernel<OUT_CH><<<dim3((N_TE + 15) / 16, OUT_CH), 1024, 0, stream>>>(xs2, ys2, zs2, tes2);
    agg_kernel<OUT_CH><<<(E_TOT * OUT_CH + 255) / 256, 256, 0, stream>>>(h2, ei, tes2, 0.5f, sums2);
    fin2_kernel<<<(N_NODES + 255) / 256, 256, 0, stream>>>(sums2, cdeg, out);
}